// Round 4
// baseline (168.532 us; speedup 1.0000x reference)
//
#include <hip/hip_runtime.h>
#include <math.h>

#define H 2048
#define E 64
#define RB 16         // rows per block (kernel 1)
#define CB 512        // h-chunk staged in LDS
#define NCH (H / CB)  // 4 chunks
#define PITCH 516     // f32 row pitch (+4 floats -> bank spread, 16B aligned)
#define TAU 1e-6f     // p-gap guard: f32 logit err <=2e-7 -> p err <=3e-9 << TAU

// ---------------- kernel 0: zero the flag counter ----------------
__global__ void zero_cnt(int* __restrict__ flags) {
    if (threadIdx.x == 0 && blockIdx.x == 0) flags[0] = 0;
}

// ---------------- kernel 1: f32 fused router + tie flagging ----------------
__global__ __launch_bounds__(256, 4)
void router_f32(const float* __restrict__ x,
                const float* __restrict__ pds,
                const float* __restrict__ Wm,
                float* __restrict__ out,
                int* __restrict__ flags)
{
    // yb [RB][PITCH] f32 (33024 B); later aliased as partials [4][RB][E] f32 (16 KB)
    __shared__ __align__(16) float yb[RB * PITCH];
    __shared__ float ssbuf[256];
    __shared__ float sfac[RB];

    const int t    = threadIdx.x;
    const int wv_i = t >> 6;       // wave 0..3 (owns 128-h subrange of each chunk)
    const int lane = t & 63;
    const int g    = lane >> 4;    // row-group -> rows {g,4+g,8+g,12+g}
    const int eg   = lane & 15;
    const int e0   = eg << 2;      // 4 experts per lane in GEMV phase

    const int row0 = blockIdx.x * RB;
    const int srow = t >> 4;       // staging row 0..15
    const int sseg = t & 15;       // staging 4-float segment

    const float* xrow = x + (size_t)(row0 + srow) * H;

    float acc[4][4];               // [row rr][e], static indexing only
#pragma unroll
    for (int a = 0; a < 4; ++a)
#pragma unroll
        for (int b = 0; b < 4; ++b) acc[a][b] = 0.0f;

    float sumsq = 0.0f;

    // prefetch chunk 0 (16 consecutive lanes -> 256B coalesced)
    float4 xv[8];
#pragma unroll
    for (int i = 0; i < 8; ++i) {
        const int hl = sseg * 4 + i * 64;
        xv[i] = *(const float4*)(xrow + hl);
    }

    for (int c = 0; c < NCH; ++c) {
        // ---- stage y = x*pds into LDS (f32); accumulate sum(x^2) ----
        const float* pbase = pds + c * CB;
#pragma unroll
        for (int i = 0; i < 8; ++i) {
            const int hl = sseg * 4 + i * 64;
            const float4 a4 = xv[i];
            const float4 p4 = *(const float4*)(pbase + hl);
            sumsq += a4.x * a4.x + a4.y * a4.y + a4.z * a4.z + a4.w * a4.w;
            float4 y4;
            y4.x = a4.x * p4.x; y4.y = a4.y * p4.y;
            y4.z = a4.z * p4.z; y4.w = a4.w * p4.w;
            *(float4*)(&yb[srow * PITCH + hl]) = y4;
        }
        __syncthreads();

        // ---- issue next chunk's x loads; latency hides under the GEMV ----
        if (c + 1 < NCH) {
            const int h0n = (c + 1) * CB;
#pragma unroll
            for (int i = 0; i < 8; ++i) {
                const int hl = sseg * 4 + i * 64;
                xv[i] = *(const float4*)(xrow + h0n + hl);
            }
        }

        // ---- f32 GEMV: 1 broadcast ds_read_b128 per row feeds 16 FMAs ----
        const int hb = wv_i * 128;
        const float* wbase = Wm + (size_t)(c * CB) * E + e0;
#pragma unroll 2
        for (int s = 0; s < 32; ++s) {
            const int hh = hb + s * 4;
            const float4 w0 = *(const float4*)(wbase + (size_t)(hh + 0) * E);
            const float4 w1 = *(const float4*)(wbase + (size_t)(hh + 1) * E);
            const float4 w2 = *(const float4*)(wbase + (size_t)(hh + 2) * E);
            const float4 w3 = *(const float4*)(wbase + (size_t)(hh + 3) * E);
#pragma unroll
            for (int rr = 0; rr < 4; ++rr) {
                const float4 y4 = *(const float4*)(&yb[(4 * rr + g) * PITCH + hh]);
                acc[rr][0] = fmaf(y4.w, w3.x, fmaf(y4.z, w2.x, fmaf(y4.y, w1.x, fmaf(y4.x, w0.x, acc[rr][0]))));
                acc[rr][1] = fmaf(y4.w, w3.y, fmaf(y4.z, w2.y, fmaf(y4.y, w1.y, fmaf(y4.x, w0.y, acc[rr][1]))));
                acc[rr][2] = fmaf(y4.w, w3.z, fmaf(y4.z, w2.z, fmaf(y4.y, w1.z, fmaf(y4.x, w0.z, acc[rr][2]))));
                acc[rr][3] = fmaf(y4.w, w3.w, fmaf(y4.z, w2.w, fmaf(y4.y, w1.w, fmaf(y4.x, w0.w, acc[rr][3]))));
            }
        }
        __syncthreads();
    }

    // ---- RMS factor per row ----
    ssbuf[t] = sumsq;
    __syncthreads();
    if (t < RB) {
        float tot = 0.0f;
#pragma unroll
        for (int i = 0; i < 16; ++i) tot += ssbuf[t * 16 + i];
        sfac[t] = rsqrtf(tot * (1.0f / (float)H) + 1e-6f) * 0.022097086912079608f;
    }

    // ---- per-wave partial logits (aliases yb; all GEMV reads done) ----
#pragma unroll
    for (int rr = 0; rr < 4; ++rr) {
        const int r = 4 * rr + g;
        *(float4*)(&yb[((wv_i * RB) + r) * E + e0]) =
            make_float4(acc[rr][0], acc[rr][1], acc[rr][2], acc[rr][3]);
    }
    __syncthreads();

    // ---- epilogue: wave wv_i owns rows 4*wv_i..+3; lane = expert ----
#pragma unroll
    for (int rr = 0; rr < 4; ++rr) {
        const int r = wv_i * 4 + rr;
        float L = yb[(0 * RB + r) * E + lane] + yb[(1 * RB + r) * E + lane]
                + yb[(2 * RB + r) * E + lane] + yb[(3 * RB + r) * E + lane];
        L *= sfac[r];

        // f32 softmax (mimics np quantization chain)
        float m = L;
#pragma unroll
        for (int off = 32; off >= 1; off >>= 1)
            m = fmaxf(m, __shfl_xor(m, off));
        const float ev = expf(L - m);
        float S = ev;
#pragma unroll
        for (int off = 32; off >= 1; off >>= 1)
            S += __shfl_xor(S, off);
        const float p = ev / S;

        // top-1 on probs, smaller-index tie-break
        float v1 = p; int i1 = lane;
#pragma unroll
        for (int off = 32; off >= 1; off >>= 1) {
            const float ov = __shfl_xor(v1, off);
            const int   oi = __shfl_xor(i1, off);
            if (ov > v1 || (ov == v1 && oi < i1)) { v1 = ov; i1 = oi; }
        }
        // top-2
        float v2 = (lane == i1) ? -1.0f : p; int i2 = lane;
#pragma unroll
        for (int off = 32; off >= 1; off >>= 1) {
            const float ov = __shfl_xor(v2, off);
            const int   oi = __shfl_xor(i2, off);
            if (ov > v2 || (ov == v2 && oi < i2)) { v2 = ov; i2 = oi; }
        }
        // top-3 value only (for the in/out boundary guard)
        float v3 = (lane == i1 || lane == i2) ? -1.0f : p;
#pragma unroll
        for (int off = 32; off >= 1; off >>= 1)
            v3 = fmaxf(v3, __shfl_xor(v3, off));

        // flag near-tie rows for the exact repair pass
        if (lane == 0 && (v2 - v3) < TAU) {
            const int k = atomicAdd(flags, 1);
            flags[1 + k] = row0 + r;
        }

        const float denom = fmaxf(v1 + v2, 1e-9f);
        const float wA = v1 / denom;
        const float wB = v2 / denom;
        const float o  = (lane == i1) ? wA : ((lane == i2) ? wB : 0.0f);
        out[(size_t)(row0 + r) * E + lane] = o;
    }
}

// ---------------- kernel 2: exact-f64 repair of flagged rows ----------------
// Replicates the round-3 (verified-passing) comparator: exact f64 logits ->
// single f32 rounding -> f32 softmax quantization -> stable top-2.
__global__ __launch_bounds__(256)
void router_fix(const float* __restrict__ x,
                const float* __restrict__ pds,
                const float* __restrict__ Wm,
                float* __restrict__ out,
                const int* __restrict__ flags)
{
    __shared__ double yd[H];        // 16 KB exact y = x*pds
    __shared__ double parts[4 * E]; // per-slice partial logits
    __shared__ double ss[256];

    const int t = threadIdx.x;
    const int count = flags[0];

    for (int j = blockIdx.x; j < count; j += gridDim.x) {
        const int r = flags[1 + j];
        const float* xr = x + (size_t)r * H;

        double s = 0.0;
#pragma unroll
        for (int i = 0; i < 8; ++i) {
            const int h = t * 8 + i;
            const double xv = (double)xr[h];
            s += xv * xv;
            yd[h] = xv * (double)pds[h];
        }
        ss[t] = s;
        __syncthreads();

        // GEMV: thread t -> expert (t&63), h-slice (t>>6); W reads coalesced
        const int ex = t & 63;
        const int sl = t >> 6;
        const float* wp = Wm + (size_t)(sl * 512) * E + ex;
        double acc = 0.0;
#pragma unroll 8
        for (int h = 0; h < 512; ++h)
            acc = fma(yd[sl * 512 + h], (double)wp[(size_t)h * E], acc);
        parts[sl * E + ex] = acc;
        __syncthreads();

        if (t < 64) {
            const int lane = t;
            double tot = ss[lane * 4] + ss[lane * 4 + 1] + ss[lane * 4 + 2] + ss[lane * 4 + 3];
#pragma unroll
            for (int off = 32; off >= 1; off >>= 1)
                tot += __shfl_xor(tot, off);
            const double sf = (1.0 / sqrt(tot * (1.0 / (double)H) + 1e-6)) * 0.022097086912079608;

            const double Ld = parts[0 * E + lane] + parts[1 * E + lane]
                            + parts[2 * E + lane] + parts[3 * E + lane];
            const float L = (float)(Ld * sf);

            float m = L;
#pragma unroll
            for (int off = 32; off >= 1; off >>= 1)
                m = fmaxf(m, __shfl_xor(m, off));
            const float ev = (float)exp((double)(L - m));
            float S = ev;
#pragma unroll
            for (int off = 32; off >= 1; off >>= 1)
                S += __shfl_xor(S, off);
            const float p = ev / S;

            float v1 = p; int i1 = lane;
#pragma unroll
            for (int off = 32; off >= 1; off >>= 1) {
                const float ov = __shfl_xor(v1, off);
                const int   oi = __shfl_xor(i1, off);
                if (ov > v1 || (ov == v1 && oi < i1)) { v1 = ov; i1 = oi; }
            }
            float v2 = (lane == i1) ? -1.0f : p; int i2 = lane;
#pragma unroll
            for (int off = 32; off >= 1; off >>= 1) {
                const float ov = __shfl_xor(v2, off);
                const int   oi = __shfl_xor(i2, off);
                if (ov > v2 || (ov == v2 && oi < i2)) { v2 = ov; i2 = oi; }
            }

            const float denom = fmaxf(v1 + v2, 1e-9f);
            const float wA = v1 / denom;
            const float wB = v2 / denom;
            const float o  = (lane == i1) ? wA : ((lane == i2) ? wB : 0.0f);
            out[(size_t)r * E + lane] = o;
        }
        __syncthreads();
    }
}

extern "C" void kernel_launch(void* const* d_in, const int* in_sizes, int n_in,
                              void* d_out, int out_size, void* d_ws, size_t ws_size,
                              hipStream_t stream) {
    const float* x   = (const float*)d_in[0];
    const float* pds = (const float*)d_in[1];
    const float* Wm  = (const float*)d_in[2];
    float* out = (float*)d_out;
    int* flags = (int*)d_ws;        // [0]=count, [1..]=row indices (<=64 KB + 4)

    const int T = in_sizes[0] / H;  // 16384
    const int grid = T / RB;        // 1024 blocks

    hipLaunchKernelGGL(zero_cnt,   dim3(1),    dim3(64),  0, stream, flags);
    hipLaunchKernelGGL(router_f32, dim3(grid), dim3(256), 0, stream, x, pds, Wm, out, flags);
    hipLaunchKernelGGL(router_fix, dim3(128),  dim3(256), 0, stream, x, pds, Wm, out, flags);
}

// Round 5
// 137.896 us; speedup vs baseline: 1.2222x; 1.2222x over previous
//
#include <hip/hip_runtime.h>
#include <math.h>

#define H 2048
#define E 64
#define RB 16         // rows per block (kernel 1)
#define CB 512        // h-chunk staged in LDS
#define NCH (H / CB)  // 4 chunks
#define PITCH 516     // f32 row pitch (+4 floats -> bank spread, 16B aligned)
#define TAU 1e-6f     // p-gap guard: f32 logit err <=2e-7 -> p err <=3e-9 << TAU

// ---------------- kernel 0: zero the flag counter ----------------
__global__ void zero_cnt(int* __restrict__ flags) {
    if (threadIdx.x == 0 && blockIdx.x == 0) flags[0] = 0;
}

// ---------------- kernel 1: f32 fused router + tie flagging ----------------
// NOTE: plain __launch_bounds__(256). Round-4's (256,4) clamped VGPRs to 64,
// spilling xv[8] -> 128 MB of scratch WRITE_SIZE and 176 us. Rounds 1-3 with
// (256) got 128 VGPRs, no spill. LDS (33.5 KB -> 4 blocks/CU) still sets
// occupancy; 128 VGPRs permits the same 16 waves/CU.
__global__ __launch_bounds__(256)
void router_f32(const float* __restrict__ x,
                const float* __restrict__ pds,
                const float* __restrict__ Wm,
                float* __restrict__ out,
                int* __restrict__ flags)
{
    // yb [RB][PITCH] f32 (33024 B); later aliased as partials [4][RB][E] f32 (16 KB)
    __shared__ __align__(16) float yb[RB * PITCH];
    __shared__ float ssbuf[256];
    __shared__ float sfac[RB];

    const int t    = threadIdx.x;
    const int wv_i = t >> 6;       // wave 0..3 (owns 128-h subrange of each chunk)
    const int lane = t & 63;
    const int g    = lane >> 4;    // row-group -> rows {g,4+g,8+g,12+g}
    const int eg   = lane & 15;
    const int e0   = eg << 2;      // 4 experts per lane in GEMV phase

    const int row0 = blockIdx.x * RB;
    const int srow = t >> 4;       // staging row 0..15
    const int sseg = t & 15;       // staging 4-float segment

    const float* xrow = x + (size_t)(row0 + srow) * H;

    float acc[4][4];               // [row rr][e], static indexing only
#pragma unroll
    for (int a = 0; a < 4; ++a)
#pragma unroll
        for (int b = 0; b < 4; ++b) acc[a][b] = 0.0f;

    float sumsq = 0.0f;

    // prefetch chunk 0 (16 consecutive lanes -> 256B coalesced)
    float4 xv[8];
#pragma unroll
    for (int i = 0; i < 8; ++i) {
        const int hl = sseg * 4 + i * 64;
        xv[i] = *(const float4*)(xrow + hl);
    }

    for (int c = 0; c < NCH; ++c) {
        // ---- stage y = x*pds into LDS (f32); accumulate sum(x^2) ----
        const float* pbase = pds + c * CB;
#pragma unroll
        for (int i = 0; i < 8; ++i) {
            const int hl = sseg * 4 + i * 64;
            const float4 a4 = xv[i];
            const float4 p4 = *(const float4*)(pbase + hl);
            sumsq += a4.x * a4.x + a4.y * a4.y + a4.z * a4.z + a4.w * a4.w;
            float4 y4;
            y4.x = a4.x * p4.x; y4.y = a4.y * p4.y;
            y4.z = a4.z * p4.z; y4.w = a4.w * p4.w;
            *(float4*)(&yb[srow * PITCH + hl]) = y4;
        }
        __syncthreads();

        // ---- issue next chunk's x loads; latency hides under the GEMV ----
        if (c + 1 < NCH) {
            const int h0n = (c + 1) * CB;
#pragma unroll
            for (int i = 0; i < 8; ++i) {
                const int hl = sseg * 4 + i * 64;
                xv[i] = *(const float4*)(xrow + h0n + hl);
            }
        }

        // ---- f32 GEMV: 1 broadcast ds_read_b128 per row feeds 16 FMAs ----
        const int hb = wv_i * 128;
        const float* wbase = Wm + (size_t)(c * CB) * E + e0;
#pragma unroll 2
        for (int s = 0; s < 32; ++s) {
            const int hh = hb + s * 4;
            const float4 w0 = *(const float4*)(wbase + (size_t)(hh + 0) * E);
            const float4 w1 = *(const float4*)(wbase + (size_t)(hh + 1) * E);
            const float4 w2 = *(const float4*)(wbase + (size_t)(hh + 2) * E);
            const float4 w3 = *(const float4*)(wbase + (size_t)(hh + 3) * E);
#pragma unroll
            for (int rr = 0; rr < 4; ++rr) {
                const float4 y4 = *(const float4*)(&yb[(4 * rr + g) * PITCH + hh]);
                acc[rr][0] = fmaf(y4.w, w3.x, fmaf(y4.z, w2.x, fmaf(y4.y, w1.x, fmaf(y4.x, w0.x, acc[rr][0]))));
                acc[rr][1] = fmaf(y4.w, w3.y, fmaf(y4.z, w2.y, fmaf(y4.y, w1.y, fmaf(y4.x, w0.y, acc[rr][1]))));
                acc[rr][2] = fmaf(y4.w, w3.z, fmaf(y4.z, w2.z, fmaf(y4.y, w1.z, fmaf(y4.x, w0.z, acc[rr][2]))));
                acc[rr][3] = fmaf(y4.w, w3.w, fmaf(y4.z, w2.w, fmaf(y4.y, w1.w, fmaf(y4.x, w0.w, acc[rr][3]))));
            }
        }
        __syncthreads();
    }

    // ---- RMS factor per row ----
    ssbuf[t] = sumsq;
    __syncthreads();
    if (t < RB) {
        float tot = 0.0f;
#pragma unroll
        for (int i = 0; i < 16; ++i) tot += ssbuf[t * 16 + i];
        sfac[t] = rsqrtf(tot * (1.0f / (float)H) + 1e-6f) * 0.022097086912079608f;
    }

    // ---- per-wave partial logits (aliases yb; all GEMV reads done) ----
#pragma unroll
    for (int rr = 0; rr < 4; ++rr) {
        const int r = 4 * rr + g;
        *(float4*)(&yb[((wv_i * RB) + r) * E + e0]) =
            make_float4(acc[rr][0], acc[rr][1], acc[rr][2], acc[rr][3]);
    }
    __syncthreads();

    // ---- epilogue: wave wv_i owns rows 4*wv_i..+3; lane = expert ----
#pragma unroll
    for (int rr = 0; rr < 4; ++rr) {
        const int r = wv_i * 4 + rr;
        float L = yb[(0 * RB + r) * E + lane] + yb[(1 * RB + r) * E + lane]
                + yb[(2 * RB + r) * E + lane] + yb[(3 * RB + r) * E + lane];
        L *= sfac[r];

        // f32 softmax (mimics np quantization chain)
        float m = L;
#pragma unroll
        for (int off = 32; off >= 1; off >>= 1)
            m = fmaxf(m, __shfl_xor(m, off));
        const float ev = expf(L - m);
        float S = ev;
#pragma unroll
        for (int off = 32; off >= 1; off >>= 1)
            S += __shfl_xor(S, off);
        const float p = ev / S;

        // top-1 on probs, smaller-index tie-break
        float v1 = p; int i1 = lane;
#pragma unroll
        for (int off = 32; off >= 1; off >>= 1) {
            const float ov = __shfl_xor(v1, off);
            const int   oi = __shfl_xor(i1, off);
            if (ov > v1 || (ov == v1 && oi < i1)) { v1 = ov; i1 = oi; }
        }
        // top-2
        float v2 = (lane == i1) ? -1.0f : p; int i2 = lane;
#pragma unroll
        for (int off = 32; off >= 1; off >>= 1) {
            const float ov = __shfl_xor(v2, off);
            const int   oi = __shfl_xor(i2, off);
            if (ov > v2 || (ov == v2 && oi < i2)) { v2 = ov; i2 = oi; }
        }
        // top-3 value only (for the in/out boundary guard)
        float v3 = (lane == i1 || lane == i2) ? -1.0f : p;
#pragma unroll
        for (int off = 32; off >= 1; off >>= 1)
            v3 = fmaxf(v3, __shfl_xor(v3, off));

        // flag near-tie rows for the exact repair pass
        if (lane == 0 && (v2 - v3) < TAU) {
            const int k = atomicAdd(flags, 1);
            flags[1 + k] = row0 + r;
        }

        const float denom = fmaxf(v1 + v2, 1e-9f);
        const float wA = v1 / denom;
        const float wB = v2 / denom;
        const float o  = (lane == i1) ? wA : ((lane == i2) ? wB : 0.0f);
        out[(size_t)(row0 + r) * E + lane] = o;
    }
}

// ---------------- kernel 2: exact-f64 repair of flagged rows ----------------
// Replicates the round-3 (verified-passing) comparator: exact f64 logits ->
// single f32 rounding -> f32 softmax quantization -> stable top-2.
__global__ __launch_bounds__(256)
void router_fix(const float* __restrict__ x,
                const float* __restrict__ pds,
                const float* __restrict__ Wm,
                float* __restrict__ out,
                const int* __restrict__ flags)
{
    __shared__ double yd[H];        // 16 KB exact y = x*pds
    __shared__ double parts[4 * E]; // per-slice partial logits
    __shared__ double ss[256];

    const int t = threadIdx.x;
    const int count = flags[0];

    for (int j = blockIdx.x; j < count; j += gridDim.x) {
        const int r = flags[1 + j];
        const float* xr = x + (size_t)r * H;

        double s = 0.0;
#pragma unroll
        for (int i = 0; i < 8; ++i) {
            const int h = t * 8 + i;
            const double xv = (double)xr[h];
            s += xv * xv;
            yd[h] = xv * (double)pds[h];
        }
        ss[t] = s;
        __syncthreads();

        // GEMV: thread t -> expert (t&63), h-slice (t>>6); W reads coalesced
        const int ex = t & 63;
        const int sl = t >> 6;
        const float* wp = Wm + (size_t)(sl * 512) * E + ex;
        double acc = 0.0;
#pragma unroll 8
        for (int h = 0; h < 512; ++h)
            acc = fma(yd[sl * 512 + h], (double)wp[(size_t)h * E], acc);
        parts[sl * E + ex] = acc;
        __syncthreads();

        if (t < 64) {
            const int lane = t;
            double tot = ss[lane * 4] + ss[lane * 4 + 1] + ss[lane * 4 + 2] + ss[lane * 4 + 3];
#pragma unroll
            for (int off = 32; off >= 1; off >>= 1)
                tot += __shfl_xor(tot, off);
            const double sf = (1.0 / sqrt(tot * (1.0 / (double)H) + 1e-6)) * 0.022097086912079608;

            const double Ld = parts[0 * E + lane] + parts[1 * E + lane]
                            + parts[2 * E + lane] + parts[3 * E + lane];
            const float L = (float)(Ld * sf);

            float m = L;
#pragma unroll
            for (int off = 32; off >= 1; off >>= 1)
                m = fmaxf(m, __shfl_xor(m, off));
            const float ev = (float)exp((double)(L - m));
            float S = ev;
#pragma unroll
            for (int off = 32; off >= 1; off >>= 1)
                S += __shfl_xor(S, off);
            const float p = ev / S;

            float v1 = p; int i1 = lane;
#pragma unroll
            for (int off = 32; off >= 1; off >>= 1) {
                const float ov = __shfl_xor(v1, off);
                const int   oi = __shfl_xor(i1, off);
                if (ov > v1 || (ov == v1 && oi < i1)) { v1 = ov; i1 = oi; }
            }
            float v2 = (lane == i1) ? -1.0f : p; int i2 = lane;
#pragma unroll
            for (int off = 32; off >= 1; off >>= 1) {
                const float ov = __shfl_xor(v2, off);
                const int   oi = __shfl_xor(i2, off);
                if (ov > v2 || (ov == v2 && oi < i2)) { v2 = ov; i2 = oi; }
            }

            const float denom = fmaxf(v1 + v2, 1e-9f);
            const float wA = v1 / denom;
            const float wB = v2 / denom;
            const float o  = (lane == i1) ? wA : ((lane == i2) ? wB : 0.0f);
            out[(size_t)r * E + lane] = o;
        }
        __syncthreads();
    }
}

extern "C" void kernel_launch(void* const* d_in, const int* in_sizes, int n_in,
                              void* d_out, int out_size, void* d_ws, size_t ws_size,
                              hipStream_t stream) {
    const float* x   = (const float*)d_in[0];
    const float* pds = (const float*)d_in[1];
    const float* Wm  = (const float*)d_in[2];
    float* out = (float*)d_out;
    int* flags = (int*)d_ws;        // [0]=count, [1..]=row indices

    const int T = in_sizes[0] / H;  // 16384
    const int grid = T / RB;        // 1024 blocks

    hipLaunchKernelGGL(zero_cnt,   dim3(1),    dim3(64),  0, stream, flags);
    hipLaunchKernelGGL(router_f32, dim3(grid), dim3(256), 0, stream, x, pds, Wm, out, flags);
    hipLaunchKernelGGL(router_fix, dim3(128),  dim3(256), 0, stream, x, pds, Wm, out, flags);
}

// Round 6
// 118.797 us; speedup vs baseline: 1.4187x; 1.1608x over previous
//
#include <hip/hip_runtime.h>
#include <math.h>

#define H 2048
#define E 64
#define TAU 1e-6f     // p-gap guard (proven round 3/5): logit err ~2.5e-7 -> p err ~4e-9 << TAU

// ---- MFMA path geometry ----
#define MT 32         // rows per block (main kernel)
#define KS 128        // k per step
#define NSTEP (H / KS)
#define LPITCH 136    // bf16 elems per LDS row (272 B = 17*16B: aligned, minimal-conflict b128)

// ---- round-5 fallback geometry ----
#define RB 16
#define CB 512
#define NCH (H / CB)
#define PITCH 516

// d_ws layout
#define FLAGS_BYTES (4 * (1 + 16384))      // 65540
#define WHI_OFF 65792u                     // 256-aligned
#define WFRAG_BYTES 262144u                // 64kc * 4n * 64lane * 8 bf16 * 2B
#define WLO_OFF (WHI_OFF + WFRAG_BYTES)
#define WS_NEEDED ((size_t)(WLO_OFF + WFRAG_BYTES))   // 590080

typedef __attribute__((ext_vector_type(8))) short short8;
typedef __attribute__((ext_vector_type(4))) float f32x4;

__device__ __forceinline__ unsigned short bf16_rne(float f) {
    unsigned u = __float_as_uint(f);
    unsigned r = u + 0x7fffu + ((u >> 16) & 1u);
    return (unsigned short)(r >> 16);
}

// ============ kernel P: split W into bf16 hi/lo MFMA B-fragment order ============
// frag elem (kc,n,lane,j) = W[kc*32 + (lane>>4)*8 + j][n*16 + (lane&15)]
__global__ __launch_bounds__(256)
void prep_w(const float* __restrict__ Wm, int* __restrict__ flags,
            unsigned short* __restrict__ whi, unsigned short* __restrict__ wlo)
{
    const int tid = blockIdx.x * 256 + threadIdx.x;   // 64 blocks -> 16384 threads
    if (tid == 0) flags[0] = 0;
    const int lane = tid & 63;
    const int fb   = tid >> 6;          // kc*4 + n
    const int kc   = fb >> 2;
    const int n    = fb & 3;
    const int r0   = kc * 32 + (lane >> 4) * 8;
    const int col  = n * 16 + (lane & 15);

    short8 hv, lv;
#pragma unroll
    for (int j = 0; j < 8; ++j) {
        const float w = Wm[(r0 + j) * E + col];
        const unsigned short hb = bf16_rne(w);
        const float hf = __uint_as_float((unsigned)hb << 16);
        const unsigned short lb = bf16_rne(w - hf);   // exact residual (Sterbenz), then RNE
        hv[j] = (short)hb;
        lv[j] = (short)lb;
    }
    *(short8*)(whi + (size_t)tid * 8) = hv;
    *(short8*)(wlo + (size_t)tid * 8) = lv;
}

// ============ kernel M: MFMA router (bf16 hi/lo split GEMM) ============
__global__ __launch_bounds__(256)
void router_mfma(const float* __restrict__ x,
                 const float* __restrict__ pds,
                 const unsigned short* __restrict__ whi,
                 const unsigned short* __restrict__ wlo,
                 float* __restrict__ out,
                 int* __restrict__ flags)
{
    __shared__ __align__(16) unsigned short yhi[MT * LPITCH];  // 8704 B
    __shared__ __align__(16) unsigned short ylo[MT * LPITCH];  // 8704 B
    __shared__ float lbuf[MT * E];                             // 8 KB logits
    __shared__ float ssbuf[256];
    __shared__ float sfac[MT];

    const int t    = threadIdx.x;
    const int wid  = t >> 6;        // wave 0..3 ; wm = wid&1 (row half), wn = wid>>1 (col half)
    const int lane = t & 63;
    const int wm   = wid & 1;
    const int wn   = wid >> 1;
    const int g    = lane >> 4;     // k-chunk group for frags
    const int row0 = blockIdx.x * MT;

    // staging: 8 threads/row, thread covers float4 at cols i*32 + (t&7)*4, i=0..3
    const int srow  = t >> 3;
    const int scol8 = t & 7;
    const float* xrow = x + (size_t)(row0 + srow) * H;

    f32x4 acc0 = {0.f, 0.f, 0.f, 0.f};  // n-frag 0 (cols wn*32 + 0..15)
    f32x4 acc1 = {0.f, 0.f, 0.f, 0.f};  // n-frag 1 (cols wn*32 + 16..31)
    float sumsq = 0.0f;

    float4 xv[4];
#pragma unroll
    for (int i = 0; i < 4; ++i)
        xv[i] = *(const float4*)(xrow + i * 32 + scol8 * 4);

    for (int c = 0; c < NSTEP; ++c) {
        // ---- convert staged regs -> bf16 hi/lo LDS tiles; accumulate sum(x^2) ----
        const float* pb = pds + c * KS;
#pragma unroll
        for (int i = 0; i < 4; ++i) {
            const int col = i * 32 + scol8 * 4;
            const float4 a4 = xv[i];
            const float4 p4 = *(const float4*)(pb + col);
            sumsq += a4.x * a4.x + a4.y * a4.y + a4.z * a4.z + a4.w * a4.w;
            float yv[4] = { a4.x * p4.x, a4.y * p4.y, a4.z * p4.z, a4.w * p4.w };
            unsigned short hb[4], lb[4];
#pragma unroll
            for (int e = 0; e < 4; ++e) {
                hb[e] = bf16_rne(yv[e]);
                const float hf = __uint_as_float((unsigned)hb[e] << 16);
                lb[e] = bf16_rne(yv[e] - hf);
            }
            const int idx = srow * LPITCH + col;
            uint2 hw, lw;
            hw.x = (unsigned)hb[0] | ((unsigned)hb[1] << 16);
            hw.y = (unsigned)hb[2] | ((unsigned)hb[3] << 16);
            lw.x = (unsigned)lb[0] | ((unsigned)lb[1] << 16);
            lw.y = (unsigned)lb[2] | ((unsigned)lb[3] << 16);
            *(uint2*)(&yhi[idx]) = hw;
            *(uint2*)(&ylo[idx]) = lw;
        }
        __syncthreads();

        // ---- prefetch next step's x ----
        if (c + 1 < NSTEP) {
            const int b = (c + 1) * KS;
#pragma unroll
            for (int i = 0; i < 4; ++i)
                xv[i] = *(const float4*)(xrow + b + i * 32 + scol8 * 4);
        }

        // ---- MFMA: 4 k-chunks of 32; acc += yhi*whi + yhi*wlo + ylo*whi ----
        const int arow = wm * 16 + (lane & 15);
#pragma unroll
        for (int kk = 0; kk < 4; ++kk) {
            const int kc = c * 4 + kk;
            const int aoff = arow * LPITCH + kk * 32 + g * 8;
            const short8 ahi = *(const short8*)(&yhi[aoff]);
            const short8 alo = *(const short8*)(&ylo[aoff]);
            const int n0 = wn * 2;
            const size_t b0 = ((size_t)(kc * 4 + n0) * 64 + lane) * 8;
            const size_t b1 = ((size_t)(kc * 4 + n0 + 1) * 64 + lane) * 8;
            const short8 bh0 = *(const short8*)(whi + b0);
            const short8 bh1 = *(const short8*)(whi + b1);
            const short8 bl0 = *(const short8*)(wlo + b0);
            const short8 bl1 = *(const short8*)(wlo + b1);
            acc0 = __builtin_amdgcn_mfma_f32_16x16x32_bf16(ahi, bh0, acc0, 0, 0, 0);
            acc0 = __builtin_amdgcn_mfma_f32_16x16x32_bf16(ahi, bl0, acc0, 0, 0, 0);
            acc0 = __builtin_amdgcn_mfma_f32_16x16x32_bf16(alo, bh0, acc0, 0, 0, 0);
            acc1 = __builtin_amdgcn_mfma_f32_16x16x32_bf16(ahi, bh1, acc1, 0, 0, 0);
            acc1 = __builtin_amdgcn_mfma_f32_16x16x32_bf16(ahi, bl1, acc1, 0, 0, 0);
            acc1 = __builtin_amdgcn_mfma_f32_16x16x32_bf16(alo, bh1, acc1, 0, 0, 0);
        }
        __syncthreads();
    }

    // ---- RMS factor per row ----
    ssbuf[t] = sumsq;
    __syncthreads();
    if (t < MT) {
        float tot = 0.0f;
#pragma unroll
        for (int i = 0; i < 8; ++i) tot += ssbuf[t * 8 + i];
        sfac[t] = rsqrtf(tot * (1.0f / (float)H) + 1e-6f) * 0.022097086912079608f;
    }

    // ---- scatter C fragments to lbuf: col=lane&15, row=(lane>>4)*4+q (m89) ----
#pragma unroll
    for (int q = 0; q < 4; ++q) {
        const int r = wm * 16 + (lane >> 4) * 4 + q;
        lbuf[r * E + wn * 32 + (lane & 15)]      = acc0[q];
        lbuf[r * E + wn * 32 + 16 + (lane & 15)] = acc1[q];
    }
    __syncthreads();

    // ---- epilogue (round-5 verified): wave wid owns rows wid*8..+8; lane=expert ----
#pragma unroll
    for (int rr = 0; rr < 8; ++rr) {
        const int r = wid * 8 + rr;
        const float L = lbuf[r * E + lane] * sfac[r];

        float m = L;
#pragma unroll
        for (int off = 32; off >= 1; off >>= 1)
            m = fmaxf(m, __shfl_xor(m, off));
        const float ev = expf(L - m);
        float S = ev;
#pragma unroll
        for (int off = 32; off >= 1; off >>= 1)
            S += __shfl_xor(S, off);
        const float p = ev / S;

        float v1 = p; int i1 = lane;
#pragma unroll
        for (int off = 32; off >= 1; off >>= 1) {
            const float ov = __shfl_xor(v1, off);
            const int   oi = __shfl_xor(i1, off);
            if (ov > v1 || (ov == v1 && oi < i1)) { v1 = ov; i1 = oi; }
        }
        float v2 = (lane == i1) ? -1.0f : p; int i2 = lane;
#pragma unroll
        for (int off = 32; off >= 1; off >>= 1) {
            const float ov = __shfl_xor(v2, off);
            const int   oi = __shfl_xor(i2, off);
            if (ov > v2 || (ov == v2 && oi < i2)) { v2 = ov; i2 = oi; }
        }
        float v3 = (lane == i1 || lane == i2) ? -1.0f : p;
#pragma unroll
        for (int off = 32; off >= 1; off >>= 1)
            v3 = fmaxf(v3, __shfl_xor(v3, off));

        if (lane == 0 && (v2 - v3) < TAU) {
            const int k = atomicAdd(flags, 1);
            flags[1 + k] = row0 + r;
        }

        const float denom = fmaxf(v1 + v2, 1e-9f);
        const float wA = v1 / denom;
        const float wB = v2 / denom;
        const float o  = (lane == i1) ? wA : ((lane == i2) ? wB : 0.0f);
        out[(size_t)(row0 + r) * E + lane] = o;
    }
}

// ============ kernel F: exact-f64 repair of flagged rows (round-3 proven) ============
__global__ __launch_bounds__(256)
void router_fix(const float* __restrict__ x,
                const float* __restrict__ pds,
                const float* __restrict__ Wm,
                float* __restrict__ out,
                const int* __restrict__ flags)
{
    __shared__ double yd[H];
    __shared__ double parts[4 * E];
    __shared__ double ss[256];

    const int t = threadIdx.x;
    const int count = flags[0];

    for (int j = blockIdx.x; j < count; j += gridDim.x) {
        const int r = flags[1 + j];
        const float* xr = x + (size_t)r * H;

        double s = 0.0;
#pragma unroll
        for (int i = 0; i < 8; ++i) {
            const int h = t * 8 + i;
            const double xv = (double)xr[h];
            s += xv * xv;
            yd[h] = xv * (double)pds[h];
        }
        ss[t] = s;
        __syncthreads();

        const int ex = t & 63;
        const int sl = t >> 6;
        const float* wp = Wm + (size_t)(sl * 512) * E + ex;
        double acc = 0.0;
#pragma unroll 8
        for (int h = 0; h < 512; ++h)
            acc = fma(yd[sl * 512 + h], (double)wp[(size_t)h * E], acc);
        parts[sl * E + ex] = acc;
        __syncthreads();

        if (t < 64) {
            const int lane = t;
            double tot = ss[lane * 4] + ss[lane * 4 + 1] + ss[lane * 4 + 2] + ss[lane * 4 + 3];
#pragma unroll
            for (int off = 32; off >= 1; off >>= 1)
                tot += __shfl_xor(tot, off);
            const double sf = (1.0 / sqrt(tot * (1.0 / (double)H) + 1e-6)) * 0.022097086912079608;

            const double Ld = parts[0 * E + lane] + parts[1 * E + lane]
                            + parts[2 * E + lane] + parts[3 * E + lane];
            const float L = (float)(Ld * sf);

            float m = L;
#pragma unroll
            for (int off = 32; off >= 1; off >>= 1)
                m = fmaxf(m, __shfl_xor(m, off));
            const float ev = (float)exp((double)(L - m));
            float S = ev;
#pragma unroll
            for (int off = 32; off >= 1; off >>= 1)
                S += __shfl_xor(S, off);
            const float p = ev / S;

            float v1 = p; int i1 = lane;
#pragma unroll
            for (int off = 32; off >= 1; off >>= 1) {
                const float ov = __shfl_xor(v1, off);
                const int   oi = __shfl_xor(i1, off);
                if (ov > v1 || (ov == v1 && oi < i1)) { v1 = ov; i1 = oi; }
            }
            float v2 = (lane == i1) ? -1.0f : p; int i2 = lane;
#pragma unroll
            for (int off = 32; off >= 1; off >>= 1) {
                const float ov = __shfl_xor(v2, off);
                const int   oi = __shfl_xor(i2, off);
                if (ov > v2 || (ov == v2 && oi < i2)) { v2 = ov; i2 = oi; }
            }

            const float denom = fmaxf(v1 + v2, 1e-9f);
            const float wA = v1 / denom;
            const float wB = v2 / denom;
            const float o  = (lane == i1) ? wA : ((lane == i2) ? wB : 0.0f);
            out[(size_t)r * E + lane] = o;
        }
        __syncthreads();
    }
}

// ============ round-5 fallback (verified, 137 us) in case ws_size is small ============
__global__ void zero_cnt(int* __restrict__ flags) {
    if (threadIdx.x == 0 && blockIdx.x == 0) flags[0] = 0;
}

__global__ __launch_bounds__(256)
void router_f32(const float* __restrict__ x,
                const float* __restrict__ pds,
                const float* __restrict__ Wm,
                float* __restrict__ out,
                int* __restrict__ flags)
{
    __shared__ __align__(16) float yb[RB * PITCH];
    __shared__ float ssbuf[256];
    __shared__ float sfac[RB];

    const int t    = threadIdx.x;
    const int wv_i = t >> 6;
    const int lane = t & 63;
    const int g    = lane >> 4;
    const int eg   = lane & 15;
    const int e0   = eg << 2;

    const int row0 = blockIdx.x * RB;
    const int srow = t >> 4;
    const int sseg = t & 15;

    const float* xrow = x + (size_t)(row0 + srow) * H;

    float acc[4][4];
#pragma unroll
    for (int a = 0; a < 4; ++a)
#pragma unroll
        for (int b = 0; b < 4; ++b) acc[a][b] = 0.0f;

    float sumsq = 0.0f;
    float4 xv[8];
#pragma unroll
    for (int i = 0; i < 8; ++i)
        xv[i] = *(const float4*)(xrow + sseg * 4 + i * 64);

    for (int c = 0; c < NCH; ++c) {
        const float* pbase = pds + c * CB;
#pragma unroll
        for (int i = 0; i < 8; ++i) {
            const int hl = sseg * 4 + i * 64;
            const float4 a4 = xv[i];
            const float4 p4 = *(const float4*)(pbase + hl);
            sumsq += a4.x * a4.x + a4.y * a4.y + a4.z * a4.z + a4.w * a4.w;
            float4 y4;
            y4.x = a4.x * p4.x; y4.y = a4.y * p4.y;
            y4.z = a4.z * p4.z; y4.w = a4.w * p4.w;
            *(float4*)(&yb[srow * PITCH + hl]) = y4;
        }
        __syncthreads();

        if (c + 1 < NCH) {
            const int h0n = (c + 1) * CB;
#pragma unroll
            for (int i = 0; i < 8; ++i)
                xv[i] = *(const float4*)(xrow + h0n + sseg * 4 + i * 64);
        }

        const int hb = wv_i * 128;
        const float* wbase = Wm + (size_t)(c * CB) * E + e0;
#pragma unroll 2
        for (int s = 0; s < 32; ++s) {
            const int hh = hb + s * 4;
            const float4 w0 = *(const float4*)(wbase + (size_t)(hh + 0) * E);
            const float4 w1 = *(const float4*)(wbase + (size_t)(hh + 1) * E);
            const float4 w2 = *(const float4*)(wbase + (size_t)(hh + 2) * E);
            const float4 w3 = *(const float4*)(wbase + (size_t)(hh + 3) * E);
#pragma unroll
            for (int rr = 0; rr < 4; ++rr) {
                const float4 y4 = *(const float4*)(&yb[(4 * rr + g) * PITCH + hh]);
                acc[rr][0] = fmaf(y4.w, w3.x, fmaf(y4.z, w2.x, fmaf(y4.y, w1.x, fmaf(y4.x, w0.x, acc[rr][0]))));
                acc[rr][1] = fmaf(y4.w, w3.y, fmaf(y4.z, w2.y, fmaf(y4.y, w1.y, fmaf(y4.x, w0.y, acc[rr][1]))));
                acc[rr][2] = fmaf(y4.w, w3.z, fmaf(y4.z, w2.z, fmaf(y4.y, w1.z, fmaf(y4.x, w0.z, acc[rr][2]))));
                acc[rr][3] = fmaf(y4.w, w3.w, fmaf(y4.z, w2.w, fmaf(y4.y, w1.w, fmaf(y4.x, w0.w, acc[rr][3]))));
            }
        }
        __syncthreads();
    }

    ssbuf[t] = sumsq;
    __syncthreads();
    if (t < RB) {
        float tot = 0.0f;
#pragma unroll
        for (int i = 0; i < 16; ++i) tot += ssbuf[t * 16 + i];
        sfac[t] = rsqrtf(tot * (1.0f / (float)H) + 1e-6f) * 0.022097086912079608f;
    }

#pragma unroll
    for (int rr = 0; rr < 4; ++rr) {
        const int r = 4 * rr + g;
        *(float4*)(&yb[((wv_i * RB) + r) * E + e0]) =
            make_float4(acc[rr][0], acc[rr][1], acc[rr][2], acc[rr][3]);
    }
    __syncthreads();

#pragma unroll
    for (int rr = 0; rr < 4; ++rr) {
        const int r = wv_i * 4 + rr;
        float L = yb[(0 * RB + r) * E + lane] + yb[(1 * RB + r) * E + lane]
                + yb[(2 * RB + r) * E + lane] + yb[(3 * RB + r) * E + lane];
        L *= sfac[r];

        float m = L;
#pragma unroll
        for (int off = 32; off >= 1; off >>= 1)
            m = fmaxf(m, __shfl_xor(m, off));
        const float ev = expf(L - m);
        float S = ev;
#pragma unroll
        for (int off = 32; off >= 1; off >>= 1)
            S += __shfl_xor(S, off);
        const float p = ev / S;

        float v1 = p; int i1 = lane;
#pragma unroll
        for (int off = 32; off >= 1; off >>= 1) {
            const float ov = __shfl_xor(v1, off);
            const int   oi = __shfl_xor(i1, off);
            if (ov > v1 || (ov == v1 && oi < i1)) { v1 = ov; i1 = oi; }
        }
        float v2 = (lane == i1) ? -1.0f : p; int i2 = lane;
#pragma unroll
        for (int off = 32; off >= 1; off >>= 1) {
            const float ov = __shfl_xor(v2, off);
            const int   oi = __shfl_xor(i2, off);
            if (ov > v2 || (ov == v2 && oi < i2)) { v2 = ov; i2 = oi; }
        }
        float v3 = (lane == i1 || lane == i2) ? -1.0f : p;
#pragma unroll
        for (int off = 32; off >= 1; off >>= 1)
            v3 = fmaxf(v3, __shfl_xor(v3, off));

        if (lane == 0 && (v2 - v3) < TAU) {
            const int k = atomicAdd(flags, 1);
            flags[1 + k] = row0 + r;
        }

        const float denom = fmaxf(v1 + v2, 1e-9f);
        const float wA = v1 / denom;
        const float wB = v2 / denom;
        const float o  = (lane == i1) ? wA : ((lane == i2) ? wB : 0.0f);
        out[(size_t)(row0 + r) * E + lane] = o;
    }
}

extern "C" void kernel_launch(void* const* d_in, const int* in_sizes, int n_in,
                              void* d_out, int out_size, void* d_ws, size_t ws_size,
                              hipStream_t stream) {
    const float* x   = (const float*)d_in[0];
    const float* pds = (const float*)d_in[1];
    const float* Wm  = (const float*)d_in[2];
    float* out = (float*)d_out;
    int* flags = (int*)d_ws;

    const int T = in_sizes[0] / H;   // 16384

    if (ws_size >= WS_NEEDED) {
        unsigned short* whi = (unsigned short*)((char*)d_ws + WHI_OFF);
        unsigned short* wlo = (unsigned short*)((char*)d_ws + WLO_OFF);
        hipLaunchKernelGGL(prep_w,      dim3(64),     dim3(256), 0, stream, Wm, flags, whi, wlo);
        hipLaunchKernelGGL(router_mfma, dim3(T / MT), dim3(256), 0, stream, x, pds, whi, wlo, out, flags);
        hipLaunchKernelGGL(router_fix,  dim3(128),    dim3(256), 0, stream, x, pds, Wm, out, flags);
    } else {
        hipLaunchKernelGGL(zero_cnt,    dim3(1),      dim3(64),  0, stream, flags);
        hipLaunchKernelGGL(router_f32,  dim3(T / RB), dim3(256), 0, stream, x, pds, Wm, out, flags);
        hipLaunchKernelGGL(router_fix,  dim3(128),    dim3(256), 0, stream, x, pds, Wm, out, flags);
    }
}

// Round 7
// 93.755 us; speedup vs baseline: 1.7976x; 1.2671x over previous
//
#include <hip/hip_runtime.h>
#include <math.h>

#define H 2048
#define E 64
#define TAU 1e-6f     // p-gap guard (proven rounds 3/5/6): logit err ~2.5e-7 -> p err ~4e-9 << TAU

// ---- MFMA path geometry ----
#define MT 16         // rows per block -> grid 1024 = 4 blocks/CU
#define KS 128        // k per step
#define NSTEP (H / KS)
#define LPITCH 136    // bf16 elems per LDS row (272 B = 17*16B -> odd 16B stride, conflict-free b128)

// ---- round-5 fallback geometry ----
#define RB 16
#define CB 512
#define NCH (H / CB)
#define PITCH 516

// d_ws layout
#define WHI_OFF 65792u                     // after flags (65540 B), 256-aligned
#define WFRAG_BYTES 262144u                // 64kc * 4n * 64lane * 8 bf16 * 2B
#define WLO_OFF (WHI_OFF + WFRAG_BYTES)
#define WS_NEEDED ((size_t)(WLO_OFF + WFRAG_BYTES))   // 590080

typedef __attribute__((ext_vector_type(8))) short short8;
typedef __attribute__((ext_vector_type(4))) float f32x4;

__device__ __forceinline__ unsigned short bf16_rne(float f) {
    unsigned u = __float_as_uint(f);
    unsigned r = u + 0x7fffu + ((u >> 16) & 1u);
    return (unsigned short)(r >> 16);
}

// ============ kernel P: split W into bf16 hi/lo MFMA B-fragment order ============
// frag elem (kc,n,lane,j) = W[kc*32 + (lane>>4)*8 + j][n*16 + (lane&15)]
__global__ __launch_bounds__(256)
void prep_w(const float* __restrict__ Wm, int* __restrict__ flags,
            unsigned short* __restrict__ whi, unsigned short* __restrict__ wlo)
{
    const int tid = blockIdx.x * 256 + threadIdx.x;   // 64 blocks -> 16384 threads
    if (tid == 0) flags[0] = 0;
    const int lane = tid & 63;
    const int fb   = tid >> 6;          // kc*4 + n
    const int kc   = fb >> 2;
    const int n    = fb & 3;
    const int r0   = kc * 32 + (lane >> 4) * 8;
    const int col  = n * 16 + (lane & 15);

    short8 hv, lv;
#pragma unroll
    for (int j = 0; j < 8; ++j) {
        const float w = Wm[(r0 + j) * E + col];
        const unsigned short hb = bf16_rne(w);
        const float hf = __uint_as_float((unsigned)hb << 16);
        const unsigned short lb = bf16_rne(w - hf);   // exact residual (Sterbenz), then RNE
        hv[j] = (short)hb;
        lv[j] = (short)lb;
    }
    *(short8*)(whi + (size_t)tid * 8) = hv;
    *(short8*)(wlo + (size_t)tid * 8) = lv;
}

// ============ kernel M: MFMA router, 16 rows/block, W reg-double-buffered ============
__global__ __launch_bounds__(256)
void router_mfma16(const float* __restrict__ x,
                   const float* __restrict__ pds,
                   const unsigned short* __restrict__ whi,
                   const unsigned short* __restrict__ wlo,
                   float* __restrict__ out,
                   int* __restrict__ flags)
{
    __shared__ __align__(16) unsigned short yhi[MT * LPITCH];  // 4352 B
    __shared__ __align__(16) unsigned short ylo[MT * LPITCH];  // 4352 B
    __shared__ float lbuf[MT * E];                             // 4 KB
    __shared__ float ssbuf[256];
    __shared__ float sfac[MT];

    const int t    = threadIdx.x;
    const int wid  = t >> 6;        // wave 0..3 = n-frag (cols wid*16..+15)
    const int lane = t & 63;
    const int row0 = blockIdx.x * MT;

    // staging: 16 threads/row, thread owns 8 contiguous cols -> 1 ds_write_b128/buffer
    const int srow = t >> 4;
    const int scol = (t & 15) * 8;
    const float* xrow = x + (size_t)(row0 + srow) * H;

    f32x4 acc = {0.f, 0.f, 0.f, 0.f};
    float sumsq = 0.0f;

    float4 xv0 = *(const float4*)(xrow + scol);
    float4 xv1 = *(const float4*)(xrow + scol + 4);

    // W double-buffer: step 0 into A
    short8 whA[4], wlA[4], whB[4], wlB[4];
#pragma unroll
    for (int kk = 0; kk < 4; ++kk) {
        const size_t off = (((size_t)(kk * 4 + wid)) * 64 + lane) * 8;
        whA[kk] = *(const short8*)(whi + off);
        wlA[kk] = *(const short8*)(wlo + off);
    }

    auto body = [&](int c, short8 (&WH)[4], short8 (&WL)[4],
                           short8 (&NH)[4], short8 (&NL)[4]) {
        // prefetch W for step c+1 (clamped re-read at the tail; harmless)
        const int cn = (c + 1 < NSTEP) ? c + 1 : c;
#pragma unroll
        for (int kk = 0; kk < 4; ++kk) {
            const size_t off = (((size_t)((cn * 4 + kk) * 4 + wid)) * 64 + lane) * 8;
            NH[kk] = *(const short8*)(whi + off);
            NL[kk] = *(const short8*)(wlo + off);
        }

        // convert staged x -> bf16 hi/lo LDS tiles; accumulate sum(x^2)
        const float* pb = pds + c * KS + scol;
        const float4 p0 = *(const float4*)(pb);
        const float4 p1 = *(const float4*)(pb + 4);
        sumsq += xv0.x * xv0.x + xv0.y * xv0.y + xv0.z * xv0.z + xv0.w * xv0.w
               + xv1.x * xv1.x + xv1.y * xv1.y + xv1.z * xv1.z + xv1.w * xv1.w;
        float y[8] = { xv0.x * p0.x, xv0.y * p0.y, xv0.z * p0.z, xv0.w * p0.w,
                       xv1.x * p1.x, xv1.y * p1.y, xv1.z * p1.z, xv1.w * p1.w };
        short8 hv, lv;
#pragma unroll
        for (int e = 0; e < 8; ++e) {
            const unsigned short hb = bf16_rne(y[e]);
            const unsigned short lb = bf16_rne(y[e] - __uint_as_float((unsigned)hb << 16));
            hv[e] = (short)hb;
            lv[e] = (short)lb;
        }
        *(short8*)(&yhi[srow * LPITCH + scol]) = hv;   // 16B-unit stride 17 -> conflict-free
        *(short8*)(&ylo[srow * LPITCH + scol]) = lv;
        __syncthreads();

        // issue next step's x loads; latency hides under MFMA + next conversion window
        const int cx = (c + 1 < NSTEP) ? c + 1 : c;
        xv0 = *(const float4*)(xrow + cx * KS + scol);
        xv1 = *(const float4*)(xrow + cx * KS + scol + 4);

        // A frags from LDS + 12 MFMAs (hi*hi + hi*lo + lo*hi)
        const int abase = (lane & 15) * LPITCH + (lane >> 4) * 8;
#pragma unroll
        for (int kk = 0; kk < 4; ++kk) {
            const short8 ah = *(const short8*)(&yhi[abase + kk * 32]);
            const short8 al = *(const short8*)(&ylo[abase + kk * 32]);
            acc = __builtin_amdgcn_mfma_f32_16x16x32_bf16(ah, WH[kk], acc, 0, 0, 0);
            acc = __builtin_amdgcn_mfma_f32_16x16x32_bf16(ah, WL[kk], acc, 0, 0, 0);
            acc = __builtin_amdgcn_mfma_f32_16x16x32_bf16(al, WH[kk], acc, 0, 0, 0);
        }
        __syncthreads();
    };

    for (int c = 0; c < NSTEP; c += 2) {
        body(c,     whA, wlA, whB, wlB);
        body(c + 1, whB, wlB, whA, wlA);
    }

    // ---- RMS factor per row ----
    ssbuf[t] = sumsq;
    __syncthreads();
    if (t < MT) {
        float tot = 0.0f;
#pragma unroll
        for (int i = 0; i < 16; ++i) tot += ssbuf[t * 16 + i];
        sfac[t] = rsqrtf(tot * (1.0f / (float)H) + 1e-6f) * 0.022097086912079608f;
    }

    // ---- scatter C frags: col=lane&15, row=(lane>>4)*4+q (m89, HW-verified r6) ----
#pragma unroll
    for (int q = 0; q < 4; ++q)
        lbuf[(((lane >> 4) * 4) + q) * E + wid * 16 + (lane & 15)] = acc[q];
    __syncthreads();

    // ---- epilogue (verified r5/r6): wave wid owns rows wid*4..+3; lane=expert ----
#pragma unroll
    for (int rr = 0; rr < 4; ++rr) {
        const int r = wid * 4 + rr;
        const float L = lbuf[r * E + lane] * sfac[r];

        float m = L;
#pragma unroll
        for (int off = 32; off >= 1; off >>= 1)
            m = fmaxf(m, __shfl_xor(m, off));
        const float ev = expf(L - m);
        float S = ev;
#pragma unroll
        for (int off = 32; off >= 1; off >>= 1)
            S += __shfl_xor(S, off);
        const float p = ev / S;

        float v1 = p; int i1 = lane;
#pragma unroll
        for (int off = 32; off >= 1; off >>= 1) {
            const float ov = __shfl_xor(v1, off);
            const int   oi = __shfl_xor(i1, off);
            if (ov > v1 || (ov == v1 && oi < i1)) { v1 = ov; i1 = oi; }
        }
        float v2 = (lane == i1) ? -1.0f : p; int i2 = lane;
#pragma unroll
        for (int off = 32; off >= 1; off >>= 1) {
            const float ov = __shfl_xor(v2, off);
            const int   oi = __shfl_xor(i2, off);
            if (ov > v2 || (ov == v2 && oi < i2)) { v2 = ov; i2 = oi; }
        }
        float v3 = (lane == i1 || lane == i2) ? -1.0f : p;
#pragma unroll
        for (int off = 32; off >= 1; off >>= 1)
            v3 = fmaxf(v3, __shfl_xor(v3, off));

        if (lane == 0 && (v2 - v3) < TAU) {
            const int k = atomicAdd(flags, 1);
            flags[1 + k] = row0 + r;
        }

        const float denom = fmaxf(v1 + v2, 1e-9f);
        const float wA = v1 / denom;
        const float wB = v2 / denom;
        const float o  = (lane == i1) ? wA : ((lane == i2) ? wB : 0.0f);
        out[(size_t)(row0 + r) * E + lane] = o;
    }
}

// ============ kernel F: exact-f64 repair of flagged rows (round-3 proven) ============
__global__ __launch_bounds__(256)
void router_fix(const float* __restrict__ x,
                const float* __restrict__ pds,
                const float* __restrict__ Wm,
                float* __restrict__ out,
                const int* __restrict__ flags)
{
    __shared__ double yd[H];
    __shared__ double parts[4 * E];
    __shared__ double ss[256];

    const int t = threadIdx.x;
    const int count = flags[0];

    for (int j = blockIdx.x; j < count; j += gridDim.x) {
        const int r = flags[1 + j];
        const float* xr = x + (size_t)r * H;

        double s = 0.0;
#pragma unroll
        for (int i = 0; i < 8; ++i) {
            const int h = t * 8 + i;
            const double xv = (double)xr[h];
            s += xv * xv;
            yd[h] = xv * (double)pds[h];
        }
        ss[t] = s;
        __syncthreads();

        const int ex = t & 63;
        const int sl = t >> 6;
        const float* wp = Wm + (size_t)(sl * 512) * E + ex;
        double acc = 0.0;
#pragma unroll 8
        for (int h = 0; h < 512; ++h)
            acc = fma(yd[sl * 512 + h], (double)wp[(size_t)h * E], acc);
        parts[sl * E + ex] = acc;
        __syncthreads();

        if (t < 64) {
            const int lane = t;
            double tot = ss[lane * 4] + ss[lane * 4 + 1] + ss[lane * 4 + 2] + ss[lane * 4 + 3];
#pragma unroll
            for (int off = 32; off >= 1; off >>= 1)
                tot += __shfl_xor(tot, off);
            const double sf = (1.0 / sqrt(tot * (1.0 / (double)H) + 1e-6)) * 0.022097086912079608;

            const double Ld = parts[0 * E + lane] + parts[1 * E + lane]
                            + parts[2 * E + lane] + parts[3 * E + lane];
            const float L = (float)(Ld * sf);

            float m = L;
#pragma unroll
            for (int off = 32; off >= 1; off >>= 1)
                m = fmaxf(m, __shfl_xor(m, off));
            const float ev = (float)exp((double)(L - m));
            float S = ev;
#pragma unroll
            for (int off = 32; off >= 1; off >>= 1)
                S += __shfl_xor(S, off);
            const float p = ev / S;

            float v1 = p; int i1 = lane;
#pragma unroll
            for (int off = 32; off >= 1; off >>= 1) {
                const float ov = __shfl_xor(v1, off);
                const int   oi = __shfl_xor(i1, off);
                if (ov > v1 || (ov == v1 && oi < i1)) { v1 = ov; i1 = oi; }
            }
            float v2 = (lane == i1) ? -1.0f : p; int i2 = lane;
#pragma unroll
            for (int off = 32; off >= 1; off >>= 1) {
                const float ov = __shfl_xor(v2, off);
                const int   oi = __shfl_xor(i2, off);
                if (ov > v2 || (ov == v2 && oi < i2)) { v2 = ov; i2 = oi; }
            }

            const float denom = fmaxf(v1 + v2, 1e-9f);
            const float wA = v1 / denom;
            const float wB = v2 / denom;
            const float o  = (lane == i1) ? wA : ((lane == i2) ? wB : 0.0f);
            out[(size_t)r * E + lane] = o;
        }
        __syncthreads();
    }
}

// ============ round-5 fallback (verified) in case ws_size is small ============
__global__ void zero_cnt(int* __restrict__ flags) {
    if (threadIdx.x == 0 && blockIdx.x == 0) flags[0] = 0;
}

__global__ __launch_bounds__(256)
void router_f32(const float* __restrict__ x,
                const float* __restrict__ pds,
                const float* __restrict__ Wm,
                float* __restrict__ out,
                int* __restrict__ flags)
{
    __shared__ __align__(16) float yb[RB * PITCH];
    __shared__ float ssbuf[256];
    __shared__ float sfac[RB];

    const int t    = threadIdx.x;
    const int wv_i = t >> 6;
    const int lane = t & 63;
    const int g    = lane >> 4;
    const int e0   = (lane & 15) << 2;

    const int row0 = blockIdx.x * RB;
    const int srow = t >> 4;
    const int sseg = t & 15;

    const float* xrow = x + (size_t)(row0 + srow) * H;

    float acc[4][4];
#pragma unroll
    for (int a = 0; a < 4; ++a)
#pragma unroll
        for (int b = 0; b < 4; ++b) acc[a][b] = 0.0f;

    float sumsq = 0.0f;
    float4 xv[8];
#pragma unroll
    for (int i = 0; i < 8; ++i)
        xv[i] = *(const float4*)(xrow + sseg * 4 + i * 64);

    for (int c = 0; c < NCH; ++c) {
        const float* pbase = pds + c * CB;
#pragma unroll
        for (int i = 0; i < 8; ++i) {
            const int hl = sseg * 4 + i * 64;
            const float4 a4 = xv[i];
            const float4 p4 = *(const float4*)(pbase + hl);
            sumsq += a4.x * a4.x + a4.y * a4.y + a4.z * a4.z + a4.w * a4.w;
            float4 y4;
            y4.x = a4.x * p4.x; y4.y = a4.y * p4.y;
            y4.z = a4.z * p4.z; y4.w = a4.w * p4.w;
            *(float4*)(&yb[srow * PITCH + hl]) = y4;
        }
        __syncthreads();

        if (c + 1 < NCH) {
            const int h0n = (c + 1) * CB;
#pragma unroll
            for (int i = 0; i < 8; ++i)
                xv[i] = *(const float4*)(xrow + h0n + sseg * 4 + i * 64);
        }

        const int hb = wv_i * 128;
        const float* wbase = Wm + (size_t)(c * CB) * E + e0;
#pragma unroll 2
        for (int s = 0; s < 32; ++s) {
            const int hh = hb + s * 4;
            const float4 w0 = *(const float4*)(wbase + (size_t)(hh + 0) * E);
            const float4 w1 = *(const float4*)(wbase + (size_t)(hh + 1) * E);
            const float4 w2 = *(const float4*)(wbase + (size_t)(hh + 2) * E);
            const float4 w3 = *(const float4*)(wbase + (size_t)(hh + 3) * E);
#pragma unroll
            for (int rr = 0; rr < 4; ++rr) {
                const float4 y4 = *(const float4*)(&yb[(4 * rr + g) * PITCH + hh]);
                acc[rr][0] = fmaf(y4.w, w3.x, fmaf(y4.z, w2.x, fmaf(y4.y, w1.x, fmaf(y4.x, w0.x, acc[rr][0]))));
                acc[rr][1] = fmaf(y4.w, w3.y, fmaf(y4.z, w2.y, fmaf(y4.y, w1.y, fmaf(y4.x, w0.y, acc[rr][1]))));
                acc[rr][2] = fmaf(y4.w, w3.z, fmaf(y4.z, w2.z, fmaf(y4.y, w1.z, fmaf(y4.x, w0.z, acc[rr][2]))));
                acc[rr][3] = fmaf(y4.w, w3.w, fmaf(y4.z, w2.w, fmaf(y4.y, w1.w, fmaf(y4.x, w0.w, acc[rr][3]))));
            }
        }
        __syncthreads();
    }

    ssbuf[t] = sumsq;
    __syncthreads();
    if (t < RB) {
        float tot = 0.0f;
#pragma unroll
        for (int i = 0; i < 16; ++i) tot += ssbuf[t * 16 + i];
        sfac[t] = rsqrtf(tot * (1.0f / (float)H) + 1e-6f) * 0.022097086912079608f;
    }

#pragma unroll
    for (int rr = 0; rr < 4; ++rr) {
        const int r = 4 * rr + g;
        *(float4*)(&yb[((wv_i * RB) + r) * E + e0]) =
            make_float4(acc[rr][0], acc[rr][1], acc[rr][2], acc[rr][3]);
    }
    __syncthreads();

#pragma unroll
    for (int rr = 0; rr < 4; ++rr) {
        const int r = wv_i * 4 + rr;
        float L = yb[(0 * RB + r) * E + lane] + yb[(1 * RB + r) * E + lane]
                + yb[(2 * RB + r) * E + lane] + yb[(3 * RB + r) * E + lane];
        L *= sfac[r];

        float m = L;
#pragma unroll
        for (int off = 32; off >= 1; off >>= 1)
            m = fmaxf(m, __shfl_xor(m, off));
        const float ev = expf(L - m);
        float S = ev;
#pragma unroll
        for (int off = 32; off >= 1; off >>= 1)
            S += __shfl_xor(S, off);
        const float p = ev / S;

        float v1 = p; int i1 = lane;
#pragma unroll
        for (int off = 32; off >= 1; off >>= 1) {
            const float ov = __shfl_xor(v1, off);
            const int   oi = __shfl_xor(i1, off);
            if (ov > v1 || (ov == v1 && oi < i1)) { v1 = ov; i1 = oi; }
        }
        float v2 = (lane == i1) ? -1.0f : p; int i2 = lane;
#pragma unroll
        for (int off = 32; off >= 1; off >>= 1) {
            const float ov = __shfl_xor(v2, off);
            const int   oi = __shfl_xor(i2, off);
            if (ov > v2 || (ov == v2 && oi < i2)) { v2 = ov; i2 = oi; }
        }
        float v3 = (lane == i1 || lane == i2) ? -1.0f : p;
#pragma unroll
        for (int off = 32; off >= 1; off >>= 1)
            v3 = fmaxf(v3, __shfl_xor(v3, off));

        if (lane == 0 && (v2 - v3) < TAU) {
            const int k = atomicAdd(flags, 1);
            flags[1 + k] = row0 + r;
        }

        const float denom = fmaxf(v1 + v2, 1e-9f);
        const float wA = v1 / denom;
        const float wB = v2 / denom;
        const float o  = (lane == i1) ? wA : ((lane == i2) ? wB : 0.0f);
        out[(size_t)(row0 + r) * E + lane] = o;
    }
}

extern "C" void kernel_launch(void* const* d_in, const int* in_sizes, int n_in,
                              void* d_out, int out_size, void* d_ws, size_t ws_size,
                              hipStream_t stream) {
    const float* x   = (const float*)d_in[0];
    const float* pds = (const float*)d_in[1];
    const float* Wm  = (const float*)d_in[2];
    float* out = (float*)d_out;
    int* flags = (int*)d_ws;

    const int T = in_sizes[0] / H;   // 16384

    if (ws_size >= WS_NEEDED) {
        unsigned short* whi = (unsigned short*)((char*)d_ws + WHI_OFF);
        unsigned short* wlo = (unsigned short*)((char*)d_ws + WLO_OFF);
        hipLaunchKernelGGL(prep_w,        dim3(64),     dim3(256), 0, stream, Wm, flags, whi, wlo);
        hipLaunchKernelGGL(router_mfma16, dim3(T / MT), dim3(256), 0, stream, x, pds, whi, wlo, out, flags);
        hipLaunchKernelGGL(router_fix,    dim3(128),    dim3(256), 0, stream, x, pds, Wm, out, flags);
    } else {
        hipLaunchKernelGGL(zero_cnt,      dim3(1),      dim3(64),  0, stream, flags);
        hipLaunchKernelGGL(router_f32,    dim3(T / RB), dim3(256), 0, stream, x, pds, Wm, out, flags);
        hipLaunchKernelGGL(router_fix,    dim3(128),    dim3(256), 0, stream, x, pds, Wm, out, flags);
    }
}

// Round 8
// 85.939 us; speedup vs baseline: 1.9611x; 1.0910x over previous
//
#include <hip/hip_runtime.h>
#include <math.h>

#define H 2048
#define E 64
#define TAU 1e-6f     // p-gap guard (proven rounds 3/5/6/7): logit err ~2.5e-7 -> p err ~4e-9 << TAU

// ---- MFMA path geometry ----
#define MT 16         // rows per block -> grid 1024 = 4 blocks/CU
#define KS 128        // k per step
#define NSTEP (H / KS)
#define LPITCH 136    // bf16 elems per LDS row (272 B = 17*16B -> odd 16B stride, conflict-free b128)

// ---- round-5 fallback geometry ----
#define RB 16
#define CB 512
#define NCH (H / CB)
#define PITCH 516

// d_ws layout
#define WHI_OFF 65792u                     // after flags (65540 B), 256-aligned
#define WFRAG_BYTES 262144u                // 64kc * 4n * 64lane * 8 bf16 * 2B
#define WLO_OFF (WHI_OFF + WFRAG_BYTES)
#define WS_NEEDED ((size_t)(WLO_OFF + WFRAG_BYTES))   // 590080

typedef __attribute__((ext_vector_type(8))) short short8;
typedef __attribute__((ext_vector_type(4))) float f32x4;

__device__ __forceinline__ unsigned short bf16_rne(float f) {
    unsigned u = __float_as_uint(f);
    unsigned r = u + 0x7fffu + ((u >> 16) & 1u);
    return (unsigned short)(r >> 16);
}

// ============ kernel P: split W into bf16 hi/lo MFMA B-fragment order ============
// frag elem (kc,n,lane,j) = W[kc*32 + (lane>>4)*8 + j][n*16 + (lane&15)]
__global__ __launch_bounds__(256)
void prep_w(const float* __restrict__ Wm, int* __restrict__ flags,
            unsigned short* __restrict__ whi, unsigned short* __restrict__ wlo)
{
    const int tid = blockIdx.x * 256 + threadIdx.x;   // 64 blocks -> 16384 threads
    if (tid == 0) flags[0] = 0;
    const int lane = tid & 63;
    const int fb   = tid >> 6;          // kc*4 + n
    const int kc   = fb >> 2;
    const int n    = fb & 3;
    const int r0   = kc * 32 + (lane >> 4) * 8;
    const int col  = n * 16 + (lane & 15);

    short8 hv, lv;
#pragma unroll
    for (int j = 0; j < 8; ++j) {
        const float w = Wm[(r0 + j) * E + col];
        const unsigned short hb = bf16_rne(w);
        const float hf = __uint_as_float((unsigned)hb << 16);
        const unsigned short lb = bf16_rne(w - hf);   // exact residual (Sterbenz), then RNE
        hv[j] = (short)hb;
        lv[j] = (short)lb;
    }
    *(short8*)(whi + (size_t)tid * 8) = hv;
    *(short8*)(wlo + (size_t)tid * 8) = lv;
}

// ============ kernel M: MFMA router, 16 rows/block, W reg-double-buffered ============
// __launch_bounds__(256, 2): round-7's plain (256) let the compiler allocate only
// 76 VGPR, spilling the 64-VGPR W double-buffer to scratch (~1 GB/dispatch of
// L2-invisible traffic -> 77 us with all pipes idle). (256,2) caps at 256 VGPR:
// the ~100 live regs fit, occupancy 4 waves/SIMD = 4 blocks/CU (same as before).
__global__ __launch_bounds__(256, 2)
void router_mfma16(const float* __restrict__ x,
                   const float* __restrict__ pds,
                   const unsigned short* __restrict__ whi,
                   const unsigned short* __restrict__ wlo,
                   float* __restrict__ out,
                   int* __restrict__ flags)
{
    __shared__ __align__(16) unsigned short yhi[MT * LPITCH];  // 4352 B
    __shared__ __align__(16) unsigned short ylo[MT * LPITCH];  // 4352 B
    __shared__ float lbuf[MT * E];                             // 4 KB
    __shared__ float ssbuf[256];
    __shared__ float sfac[MT];

    const int t    = threadIdx.x;
    const int wid  = t >> 6;        // wave 0..3 = n-frag (cols wid*16..+15)
    const int lane = t & 63;
    const int row0 = blockIdx.x * MT;

    // staging: 16 threads/row, thread owns 8 contiguous cols -> 1 ds_write_b128/buffer
    const int srow = t >> 4;
    const int scol = (t & 15) * 8;
    const float* xrow = x + (size_t)(row0 + srow) * H;

    f32x4 acc = {0.f, 0.f, 0.f, 0.f};
    float sumsq = 0.0f;

    float4 xv0 = *(const float4*)(xrow + scol);
    float4 xv1 = *(const float4*)(xrow + scol + 4);

    // W double-buffer: step 0 into A
    short8 whA[4], wlA[4], whB[4], wlB[4];
#pragma unroll
    for (int kk = 0; kk < 4; ++kk) {
        const size_t off = (((size_t)(kk * 4 + wid)) * 64 + lane) * 8;
        whA[kk] = *(const short8*)(whi + off);
        wlA[kk] = *(const short8*)(wlo + off);
    }

    auto body = [&](int c, short8 (&WH)[4], short8 (&WL)[4],
                           short8 (&NH)[4], short8 (&NL)[4]) {
        // prefetch W for step c+1 (clamped re-read at the tail; harmless)
        const int cn = (c + 1 < NSTEP) ? c + 1 : c;
#pragma unroll
        for (int kk = 0; kk < 4; ++kk) {
            const size_t off = (((size_t)((cn * 4 + kk) * 4 + wid)) * 64 + lane) * 8;
            NH[kk] = *(const short8*)(whi + off);
            NL[kk] = *(const short8*)(wlo + off);
        }

        // convert staged x -> bf16 hi/lo LDS tiles; accumulate sum(x^2)
        const float* pb = pds + c * KS + scol;
        const float4 p0 = *(const float4*)(pb);
        const float4 p1 = *(const float4*)(pb + 4);
        sumsq += xv0.x * xv0.x + xv0.y * xv0.y + xv0.z * xv0.z + xv0.w * xv0.w
               + xv1.x * xv1.x + xv1.y * xv1.y + xv1.z * xv1.z + xv1.w * xv1.w;
        float y[8] = { xv0.x * p0.x, xv0.y * p0.y, xv0.z * p0.z, xv0.w * p0.w,
                       xv1.x * p1.x, xv1.y * p1.y, xv1.z * p1.z, xv1.w * p1.w };
        short8 hv, lv;
#pragma unroll
        for (int e = 0; e < 8; ++e) {
            const unsigned short hb = bf16_rne(y[e]);
            const unsigned short lb = bf16_rne(y[e] - __uint_as_float((unsigned)hb << 16));
            hv[e] = (short)hb;
            lv[e] = (short)lb;
        }
        *(short8*)(&yhi[srow * LPITCH + scol]) = hv;   // 16B-unit stride 17 -> conflict-free
        *(short8*)(&ylo[srow * LPITCH + scol]) = lv;
        __syncthreads();

        // issue next step's x loads; latency hides under MFMA + next conversion window
        const int cx = (c + 1 < NSTEP) ? c + 1 : c;
        xv0 = *(const float4*)(xrow + cx * KS + scol);
        xv1 = *(const float4*)(xrow + cx * KS + scol + 4);

        // A frags from LDS + 12 MFMAs (hi*hi + hi*lo + lo*hi)
        const int abase = (lane & 15) * LPITCH + (lane >> 4) * 8;
#pragma unroll
        for (int kk = 0; kk < 4; ++kk) {
            const short8 ah = *(const short8*)(&yhi[abase + kk * 32]);
            const short8 al = *(const short8*)(&ylo[abase + kk * 32]);
            acc = __builtin_amdgcn_mfma_f32_16x16x32_bf16(ah, WH[kk], acc, 0, 0, 0);
            acc = __builtin_amdgcn_mfma_f32_16x16x32_bf16(ah, WL[kk], acc, 0, 0, 0);
            acc = __builtin_amdgcn_mfma_f32_16x16x32_bf16(al, WH[kk], acc, 0, 0, 0);
        }
        __syncthreads();
    };

    for (int c = 0; c < NSTEP; c += 2) {
        body(c,     whA, wlA, whB, wlB);
        body(c + 1, whB, wlB, whA, wlA);
    }

    // ---- RMS factor per row ----
    ssbuf[t] = sumsq;
    __syncthreads();
    if (t < MT) {
        float tot = 0.0f;
#pragma unroll
        for (int i = 0; i < 16; ++i) tot += ssbuf[t * 16 + i];
        sfac[t] = rsqrtf(tot * (1.0f / (float)H) + 1e-6f) * 0.022097086912079608f;
    }

    // ---- scatter C frags: col=lane&15, row=(lane>>4)*4+q (m89, HW-verified r6/r7) ----
#pragma unroll
    for (int q = 0; q < 4; ++q)
        lbuf[(((lane >> 4) * 4) + q) * E + wid * 16 + (lane & 15)] = acc[q];
    __syncthreads();

    // ---- epilogue (verified r5/r6/r7): wave wid owns rows wid*4..+3; lane=expert ----
#pragma unroll
    for (int rr = 0; rr < 4; ++rr) {
        const int r = wid * 4 + rr;
        const float L = lbuf[r * E + lane] * sfac[r];

        float m = L;
#pragma unroll
        for (int off = 32; off >= 1; off >>= 1)
            m = fmaxf(m, __shfl_xor(m, off));
        const float ev = expf(L - m);
        float S = ev;
#pragma unroll
        for (int off = 32; off >= 1; off >>= 1)
            S += __shfl_xor(S, off);
        const float p = ev / S;

        float v1 = p; int i1 = lane;
#pragma unroll
        for (int off = 32; off >= 1; off >>= 1) {
            const float ov = __shfl_xor(v1, off);
            const int   oi = __shfl_xor(i1, off);
            if (ov > v1 || (ov == v1 && oi < i1)) { v1 = ov; i1 = oi; }
        }
        float v2 = (lane == i1) ? -1.0f : p; int i2 = lane;
#pragma unroll
        for (int off = 32; off >= 1; off >>= 1) {
            const float ov = __shfl_xor(v2, off);
            const int   oi = __shfl_xor(i2, off);
            if (ov > v2 || (ov == v2 && oi < i2)) { v2 = ov; i2 = oi; }
        }
        float v3 = (lane == i1 || lane == i2) ? -1.0f : p;
#pragma unroll
        for (int off = 32; off >= 1; off >>= 1)
            v3 = fmaxf(v3, __shfl_xor(v3, off));

        if (lane == 0 && (v2 - v3) < TAU) {
            const int k = atomicAdd(flags, 1);
            flags[1 + k] = row0 + r;
        }

        const float denom = fmaxf(v1 + v2, 1e-9f);
        const float wA = v1 / denom;
        const float wB = v2 / denom;
        const float o  = (lane == i1) ? wA : ((lane == i2) ? wB : 0.0f);
        out[(size_t)(row0 + r) * E + lane] = o;
    }
}

// ============ kernel F: exact-f64 repair of flagged rows (round-3 proven) ============
__global__ __launch_bounds__(256)
void router_fix(const float* __restrict__ x,
                const float* __restrict__ pds,
                const float* __restrict__ Wm,
                float* __restrict__ out,
                const int* __restrict__ flags)
{
    __shared__ double yd[H];
    __shared__ double parts[4 * E];
    __shared__ double ss[256];

    const int t = threadIdx.x;
    const int count = flags[0];

    for (int j = blockIdx.x; j < count; j += gridDim.x) {
        const int r = flags[1 + j];
        const float* xr = x + (size_t)r * H;

        double s = 0.0;
#pragma unroll
        for (int i = 0; i < 8; ++i) {
            const int h = t * 8 + i;
            const double xv = (double)xr[h];
            s += xv * xv;
            yd[h] = xv * (double)pds[h];
        }
        ss[t] = s;
        __syncthreads();

        const int ex = t & 63;
        const int sl = t >> 6;
        const float* wp = Wm + (size_t)(sl * 512) * E + ex;
        double acc = 0.0;
#pragma unroll 8
        for (int h = 0; h < 512; ++h)
            acc = fma(yd[sl * 512 + h], (double)wp[(size_t)h * E], acc);
        parts[sl * E + ex] = acc;
        __syncthreads();

        if (t < 64) {
            const int lane = t;
            double tot = ss[lane * 4] + ss[lane * 4 + 1] + ss[lane * 4 + 2] + ss[lane * 4 + 3];
#pragma unroll
            for (int off = 32; off >= 1; off >>= 1)
                tot += __shfl_xor(tot, off);
            const double sf = (1.0 / sqrt(tot * (1.0 / (double)H) + 1e-6)) * 0.022097086912079608;

            const double Ld = parts[0 * E + lane] + parts[1 * E + lane]
                            + parts[2 * E + lane] + parts[3 * E + lane];
            const float L = (float)(Ld * sf);

            float m = L;
#pragma unroll
            for (int off = 32; off >= 1; off >>= 1)
                m = fmaxf(m, __shfl_xor(m, off));
            const float ev = (float)exp((double)(L - m));
            float S = ev;
#pragma unroll
            for (int off = 32; off >= 1; off >>= 1)
                S += __shfl_xor(S, off);
            const float p = ev / S;

            float v1 = p; int i1 = lane;
#pragma unroll
            for (int off = 32; off >= 1; off >>= 1) {
                const float ov = __shfl_xor(v1, off);
                const int   oi = __shfl_xor(i1, off);
                if (ov > v1 || (ov == v1 && oi < i1)) { v1 = ov; i1 = oi; }
            }
            float v2 = (lane == i1) ? -1.0f : p; int i2 = lane;
#pragma unroll
            for (int off = 32; off >= 1; off >>= 1) {
                const float ov = __shfl_xor(v2, off);
                const int   oi = __shfl_xor(i2, off);
                if (ov > v2 || (ov == v2 && oi < i2)) { v2 = ov; i2 = oi; }
            }

            const float denom = fmaxf(v1 + v2, 1e-9f);
            const float wA = v1 / denom;
            const float wB = v2 / denom;
            const float o  = (lane == i1) ? wA : ((lane == i2) ? wB : 0.0f);
            out[(size_t)r * E + lane] = o;
        }
        __syncthreads();
    }
}

// ============ round-5 fallback (verified) in case ws_size is small ============
__global__ void zero_cnt(int* __restrict__ flags) {
    if (threadIdx.x == 0 && blockIdx.x == 0) flags[0] = 0;
}

__global__ __launch_bounds__(256)
void router_f32(const float* __restrict__ x,
                const float* __restrict__ pds,
                const float* __restrict__ Wm,
                float* __restrict__ out,
                int* __restrict__ flags)
{
    __shared__ __align__(16) float yb[RB * PITCH];
    __shared__ float ssbuf[256];
    __shared__ float sfac[RB];

    const int t    = threadIdx.x;
    const int wv_i = t >> 6;
    const int lane = t & 63;
    const int g    = lane >> 4;
    const int e0   = (lane & 15) << 2;

    const int row0 = blockIdx.x * RB;
    const int srow = t >> 4;
    const int sseg = t & 15;

    const float* xrow = x + (size_t)(row0 + srow) * H;

    float acc[4][4];
#pragma unroll
    for (int a = 0; a < 4; ++a)
#pragma unroll
        for (int b = 0; b < 4; ++b) acc[a][b] = 0.0f;

    float sumsq = 0.0f;
    float4 xv[8];
#pragma unroll
    for (int i = 0; i < 8; ++i)
        xv[i] = *(const float4*)(xrow + sseg * 4 + i * 64);

    for (int c = 0; c < NCH; ++c) {
        const float* pbase = pds + c * CB;
#pragma unroll
        for (int i = 0; i < 8; ++i) {
            const int hl = sseg * 4 + i * 64;
            const float4 a4 = xv[i];
            const float4 p4 = *(const float4*)(pbase + hl);
            sumsq += a4.x * a4.x + a4.y * a4.y + a4.z * a4.z + a4.w * a4.w;
            float4 y4;
            y4.x = a4.x * p4.x; y4.y = a4.y * p4.y;
            y4.z = a4.z * p4.z; y4.w = a4.w * p4.w;
            *(float4*)(&yb[srow * PITCH + hl]) = y4;
        }
        __syncthreads();

        if (c + 1 < NCH) {
            const int h0n = (c + 1) * CB;
#pragma unroll
            for (int i = 0; i < 8; ++i)
                xv[i] = *(const float4*)(xrow + h0n + sseg * 4 + i * 64);
        }

        const int hb = wv_i * 128;
        const float* wbase = Wm + (size_t)(c * CB) * E + e0;
#pragma unroll 2
        for (int s = 0; s < 32; ++s) {
            const int hh = hb + s * 4;
            const float4 w0 = *(const float4*)(wbase + (size_t)(hh + 0) * E);
            const float4 w1 = *(const float4*)(wbase + (size_t)(hh + 1) * E);
            const float4 w2 = *(const float4*)(wbase + (size_t)(hh + 2) * E);
            const float4 w3 = *(const float4*)(wbase + (size_t)(hh + 3) * E);
#pragma unroll
            for (int rr = 0; rr < 4; ++rr) {
                const float4 y4 = *(const float4*)(&yb[(4 * rr + g) * PITCH + hh]);
                acc[rr][0] = fmaf(y4.w, w3.x, fmaf(y4.z, w2.x, fmaf(y4.y, w1.x, fmaf(y4.x, w0.x, acc[rr][0]))));
                acc[rr][1] = fmaf(y4.w, w3.y, fmaf(y4.z, w2.y, fmaf(y4.y, w1.y, fmaf(y4.x, w0.y, acc[rr][1]))));
                acc[rr][2] = fmaf(y4.w, w3.z, fmaf(y4.z, w2.z, fmaf(y4.y, w1.z, fmaf(y4.x, w0.z, acc[rr][2]))));
                acc[rr][3] = fmaf(y4.w, w3.w, fmaf(y4.z, w2.w, fmaf(y4.y, w1.w, fmaf(y4.x, w0.w, acc[rr][3]))));
            }
        }
        __syncthreads();
    }

    ssbuf[t] = sumsq;
    __syncthreads();
    if (t < RB) {
        float tot = 0.0f;
#pragma unroll
        for (int i = 0; i < 16; ++i) tot += ssbuf[t * 16 + i];
        sfac[t] = rsqrtf(tot * (1.0f / (float)H) + 1e-6f) * 0.022097086912079608f;
    }

#pragma unroll
    for (int rr = 0; rr < 4; ++rr) {
        const int r = 4 * rr + g;
        *(float4*)(&yb[((wv_i * RB) + r) * E + e0]) =
            make_float4(acc[rr][0], acc[rr][1], acc[rr][2], acc[rr][3]);
    }
    __syncthreads();

#pragma unroll
    for (int rr = 0; rr < 4; ++rr) {
        const int r = wv_i * 4 + rr;
        float L = yb[(0 * RB + r) * E + lane] + yb[(1 * RB + r) * E + lane]
                + yb[(2 * RB + r) * E + lane] + yb[(3 * RB + r) * E + lane];
        L *= sfac[r];

        float m = L;
#pragma unroll
        for (int off = 32; off >= 1; off >>= 1)
            m = fmaxf(m, __shfl_xor(m, off));
        const float ev = expf(L - m);
        float S = ev;
#pragma unroll
        for (int off = 32; off >= 1; off >>= 1)
            S += __shfl_xor(S, off);
        const float p = ev / S;

        float v1 = p; int i1 = lane;
#pragma unroll
        for (int off = 32; off >= 1; off >>= 1) {
            const float ov = __shfl_xor(v1, off);
            const int   oi = __shfl_xor(i1, off);
            if (ov > v1 || (ov == v1 && oi < i1)) { v1 = ov; i1 = oi; }
        }
        float v2 = (lane == i1) ? -1.0f : p; int i2 = lane;
#pragma unroll
        for (int off = 32; off >= 1; off >>= 1) {
            const float ov = __shfl_xor(v2, off);
            const int   oi = __shfl_xor(i2, off);
            if (ov > v2 || (ov == v2 && oi < i2)) { v2 = ov; i2 = oi; }
        }
        float v3 = (lane == i1 || lane == i2) ? -1.0f : p;
#pragma unroll
        for (int off = 32; off >= 1; off >>= 1)
            v3 = fmaxf(v3, __shfl_xor(v3, off));

        if (lane == 0 && (v2 - v3) < TAU) {
            const int k = atomicAdd(flags, 1);
            flags[1 + k] = row0 + r;
        }

        const float denom = fmaxf(v1 + v2, 1e-9f);
        const float wA = v1 / denom;
        const float wB = v2 / denom;
        const float o  = (lane == i1) ? wA : ((lane == i2) ? wB : 0.0f);
        out[(size_t)(row0 + r) * E + lane] = o;
    }
}

extern "C" void kernel_launch(void* const* d_in, const int* in_sizes, int n_in,
                              void* d_out, int out_size, void* d_ws, size_t ws_size,
                              hipStream_t stream) {
    const float* x   = (const float*)d_in[0];
    const float* pds = (const float*)d_in[1];
    const float* Wm  = (const float*)d_in[2];
    float* out = (float*)d_out;
    int* flags = (int*)d_ws;

    const int T = in_sizes[0] / H;   // 16384

    if (ws_size >= WS_NEEDED) {
        unsigned short* whi = (unsigned short*)((char*)d_ws + WHI_OFF);
        unsigned short* wlo = (unsigned short*)((char*)d_ws + WLO_OFF);
        hipLaunchKernelGGL(prep_w,        dim3(64),     dim3(256), 0, stream, Wm, flags, whi, wlo);
        hipLaunchKernelGGL(router_mfma16, dim3(T / MT), dim3(256), 0, stream, x, pds, whi, wlo, out, flags);
        hipLaunchKernelGGL(router_fix,    dim3(128),    dim3(256), 0, stream, x, pds, Wm, out, flags);
    } else {
        hipLaunchKernelGGL(zero_cnt,      dim3(1),      dim3(64),  0, stream, flags);
        hipLaunchKernelGGL(router_f32,    dim3(T / RB), dim3(256), 0, stream, x, pds, Wm, out, flags);
        hipLaunchKernelGGL(router_fix,    dim3(128),    dim3(256), 0, stream, x, pds, Wm, out, flags);
    }
}

// Round 9
// 85.902 us; speedup vs baseline: 1.9619x; 1.0004x over previous
//
#include <hip/hip_runtime.h>
#include <math.h>

#define H 2048
#define E 64
#define TAU 1e-6f     // p-gap guard (proven r3/5/6/7/8): logit err ~2.5e-7 -> p err ~4e-9 << TAU

// ---- MFMA path geometry ----
#define MT 16         // rows per block -> grid 1024 = 4 blocks/CU
#define NST 4         // K-steps per wave (each 128 k; wave owns K-quarter 512)

// ---- round-5 fallback geometry ----
#define RB 16
#define CB 512
#define NCH (H / CB)
#define PITCH 516

// d_ws layout
#define WHI_OFF 65792u                     // after flags (65540 B), 256-aligned
#define WFRAG_BYTES 262144u                // 64kc * 4n * 64lane * 8 bf16 * 2B
#define WLO_OFF (WHI_OFF + WFRAG_BYTES)
#define WS_NEEDED ((size_t)(WLO_OFF + WFRAG_BYTES))   // 590080

typedef __attribute__((ext_vector_type(8))) short short8;
typedef __attribute__((ext_vector_type(4))) float f32x4;

__device__ __forceinline__ unsigned short bf16_rne(float f) {
    unsigned u = __float_as_uint(f);
    unsigned r = u + 0x7fffu + ((u >> 16) & 1u);
    return (unsigned short)(r >> 16);
}

// ============ kernel P: split W into bf16 hi/lo MFMA B-fragment order ============
// frag elem (kc,n,lane,j) = W[kc*32 + (lane>>4)*8 + j][n*16 + (lane&15)]
__global__ __launch_bounds__(256)
void prep_w(const float* __restrict__ Wm, int* __restrict__ flags,
            unsigned short* __restrict__ whi, unsigned short* __restrict__ wlo)
{
    const int tid = blockIdx.x * 256 + threadIdx.x;   // 64 blocks -> 16384 threads
    if (tid == 0) flags[0] = 0;
    const int lane = tid & 63;
    const int fb   = tid >> 6;          // kc*4 + n
    const int kc   = fb >> 2;
    const int n    = fb & 3;
    const int r0   = kc * 32 + (lane >> 4) * 8;
    const int col  = n * 16 + (lane & 15);

    short8 hv, lv;
#pragma unroll
    for (int j = 0; j < 8; ++j) {
        const float w = Wm[(r0 + j) * E + col];
        const unsigned short hb = bf16_rne(w);
        const float hf = __uint_as_float((unsigned)hb << 16);
        const unsigned short lb = bf16_rne(w - hf);   // exact residual (Sterbenz), then RNE
        hv[j] = (short)hb;
        lv[j] = (short)lb;
    }
    *(short8*)(whi + (size_t)tid * 8) = hv;
    *(short8*)(wlo + (size_t)tid * 8) = lv;
}

// ============ kernel M: barrier-free K-split MFMA router ============
// Wave w owns K in [512w, 512w+512) for ALL 64 experts; private LDS staging
// region per wave -> ZERO __syncthreads in the K-loop (r6-r8's 2-barrier/step
// structure exposed ~400cy x-load latency after each barrier with nothing to
// cover it -> all pipes <20%). 4 independent waves/SIMD now latency-hide by TLP.
__global__ __launch_bounds__(256, 2)
void router_nb(const float* __restrict__ x,
               const float* __restrict__ pds,
               const unsigned short* __restrict__ whi,
               const unsigned short* __restrict__ wlo,
               float* __restrict__ out,
               int* __restrict__ flags)
{
    // [wave][hi/lo][kcl][16*32 + 8 pad] bf16; 8320 B/wave, 33280 B total.
    // After the K-loop each wave's region is dead -> aliased as its lbuf
    // (16 rows x 64 experts f32 partial logits, 4096 B).
    __shared__ __align__(16) unsigned short ybuf[4][2][4][520];
    __shared__ float ssbuf[64];
    __shared__ float sfac[16];

    const int t    = threadIdx.x;
    const int wid  = t >> 6;
    const int lane = t & 63;
    const int lgrp = lane >> 4;          // 0..3
    const int lsub = lane & 15;          // 0..15
    const int row0 = blockIdx.x * MT;

    const int kcl_w  = lsub >> 2;        // staging subtile
    const int koff_w = (lsub & 3) * 8;   // staging k-offset in subtile
    const int kbase  = wid * 512;        // this wave's K range

    f32x4 acc[4] = {{0.f,0.f,0.f,0.f},{0.f,0.f,0.f,0.f},
                    {0.f,0.f,0.f,0.f},{0.f,0.f,0.f,0.f}};
    float sq[4] = {0.f, 0.f, 0.f, 0.f};

    // x load pattern: lane covers rows {rr*4+lgrp}, cols lsub*8..+8 of the step.
    // 16-lane group -> 512 B contiguous per row: coalesced.
    float4 xv[4][2];
#pragma unroll
    for (int rr = 0; rr < 4; ++rr) {
        const float* p = x + (size_t)(row0 + rr * 4 + lgrp) * H + kbase + lsub * 8;
        xv[rr][0] = *(const float4*)p;
        xv[rr][1] = *(const float4*)(p + 4);
    }

    for (int st = 0; st < NST; ++st) {
        // ---- convert current step's x -> private bf16 hi/lo subtiles ----
        const float* pb = pds + kbase + st * 128 + lsub * 8;
        const float4 p0 = *(const float4*)pb;
        const float4 p1 = *(const float4*)(pb + 4);
#pragma unroll
        for (int rr = 0; rr < 4; ++rr) {
            const float4 a0 = xv[rr][0];
            const float4 a1 = xv[rr][1];
            sq[rr] += a0.x * a0.x + a0.y * a0.y + a0.z * a0.z + a0.w * a0.w
                    + a1.x * a1.x + a1.y * a1.y + a1.z * a1.z + a1.w * a1.w;
            const float y[8] = { a0.x * p0.x, a0.y * p0.y, a0.z * p0.z, a0.w * p0.w,
                                 a1.x * p1.x, a1.y * p1.y, a1.z * p1.z, a1.w * p1.w };
            short8 hv, lv;
#pragma unroll
            for (int e = 0; e < 8; ++e) {
                const unsigned short hb = bf16_rne(y[e]);
                const unsigned short lb = bf16_rne(y[e] - __uint_as_float((unsigned)hb << 16));
                hv[e] = (short)hb;
                lv[e] = (short)lb;
            }
            const int didx = (rr * 4 + lgrp) * 32 + koff_w;
            *(short8*)(&ybuf[wid][0][kcl_w][didx]) = hv;
            *(short8*)(&ybuf[wid][1][kcl_w][didx]) = lv;
        }

        // ---- issue next step's x loads; MFMA phase below hides the latency ----
        if (st + 1 < NST) {
#pragma unroll
            for (int rr = 0; rr < 4; ++rr) {
                const float* p = x + (size_t)(row0 + rr * 4 + lgrp) * H
                               + kbase + (st + 1) * 128 + lsub * 8;
                xv[rr][0] = *(const float4*)p;
                xv[rr][1] = *(const float4*)(p + 4);
            }
        }

        // ---- 4 k-chunks: W frags from L2 + own-A from LDS + 12 MFMAs each ----
        // (in-wave ds_write->ds_read ordering guaranteed via lgkmcnt; no barrier)
        const int aoff = lsub * 32 + lgrp * 8;
#pragma unroll
        for (int kcl = 0; kcl < 4; ++kcl) {
            const int kc = wid * 16 + st * 4 + kcl;
            const unsigned short* wbh = whi + (size_t)kc * 2048 + lane * 8;
            const unsigned short* wbl = wlo + (size_t)kc * 2048 + lane * 8;
            short8 bh[4], bl[4];
#pragma unroll
            for (int n = 0; n < 4; ++n) {
                bh[n] = *(const short8*)(wbh + n * 512);
                bl[n] = *(const short8*)(wbl + n * 512);
            }
            const short8 ah = *(const short8*)(&ybuf[wid][0][kcl][aoff]);
            const short8 al = *(const short8*)(&ybuf[wid][1][kcl][aoff]);
#pragma unroll
            for (int n = 0; n < 4; ++n) {
                acc[n] = __builtin_amdgcn_mfma_f32_16x16x32_bf16(ah, bh[n], acc[n], 0, 0, 0);
                acc[n] = __builtin_amdgcn_mfma_f32_16x16x32_bf16(ah, bl[n], acc[n], 0, 0, 0);
                acc[n] = __builtin_amdgcn_mfma_f32_16x16x32_bf16(al, bh[n], acc[n], 0, 0, 0);
            }
        }
    }

    // ---- per-wave partial logits into own region (aliases dead staging) ----
    // C frag: col=lane&15, row=(lane>>4)*4+q (m89, HW-verified r6-r8)
    float* lb = (float*)ybuf;                 // wave stride 2080 floats
    float* lw = lb + wid * 2080;
#pragma unroll
    for (int n = 0; n < 4; ++n)
#pragma unroll
        for (int q = 0; q < 4; ++q)
            lw[(lgrp * 4 + q) * 64 + n * 16 + lsub] = acc[n][q];

    // ---- per-wave sum(x^2) partials: reduce over the 16-lane col group ----
#pragma unroll
    for (int rr = 0; rr < 4; ++rr) {
        float s = sq[rr];
        s += __shfl_xor(s, 1);
        s += __shfl_xor(s, 2);
        s += __shfl_xor(s, 4);
        s += __shfl_xor(s, 8);
        if (lsub == 0) ssbuf[wid * 16 + rr * 4 + lgrp] = s;
    }
    __syncthreads();                          // the kernel's single K-side barrier

    if (t < 16) {
        const float tot = ssbuf[t] + ssbuf[16 + t] + ssbuf[32 + t] + ssbuf[48 + t];
        sfac[t] = rsqrtf(tot * (1.0f / (float)H) + 1e-6f) * 0.022097086912079608f;
    }
    __syncthreads();

    // ---- epilogue (verified r5-r8): wave wid owns rows wid*4..+3; lane=expert ----
#pragma unroll
    for (int rr = 0; rr < 4; ++rr) {
        const int r = wid * 4 + rr;
        const float L = (lb[r * 64 + lane]        + lb[2080 + r * 64 + lane]
                       + lb[4160 + r * 64 + lane] + lb[6240 + r * 64 + lane]) * sfac[r];

        float m = L;
#pragma unroll
        for (int off = 32; off >= 1; off >>= 1)
            m = fmaxf(m, __shfl_xor(m, off));
        const float ev = expf(L - m);
        float S = ev;
#pragma unroll
        for (int off = 32; off >= 1; off >>= 1)
            S += __shfl_xor(S, off);
        const float p = ev / S;

        float v1 = p; int i1 = lane;
#pragma unroll
        for (int off = 32; off >= 1; off >>= 1) {
            const float ov = __shfl_xor(v1, off);
            const int   oi = __shfl_xor(i1, off);
            if (ov > v1 || (ov == v1 && oi < i1)) { v1 = ov; i1 = oi; }
        }
        float v2 = (lane == i1) ? -1.0f : p; int i2 = lane;
#pragma unroll
        for (int off = 32; off >= 1; off >>= 1) {
            const float ov = __shfl_xor(v2, off);
            const int   oi = __shfl_xor(i2, off);
            if (ov > v2 || (ov == v2 && oi < i2)) { v2 = ov; i2 = oi; }
        }
        float v3 = (lane == i1 || lane == i2) ? -1.0f : p;
#pragma unroll
        for (int off = 32; off >= 1; off >>= 1)
            v3 = fmaxf(v3, __shfl_xor(v3, off));

        if (lane == 0 && (v2 - v3) < TAU) {
            const int k = atomicAdd(flags, 1);
            flags[1 + k] = row0 + r;
        }

        const float denom = fmaxf(v1 + v2, 1e-9f);
        const float wA = v1 / denom;
        const float wB = v2 / denom;
        const float o  = (lane == i1) ? wA : ((lane == i2) ? wB : 0.0f);
        out[(size_t)(row0 + r) * E + lane] = o;
    }
}

// ============ kernel F: exact-f64 repair of flagged rows (round-3 proven) ============
__global__ __launch_bounds__(256)
void router_fix(const float* __restrict__ x,
                const float* __restrict__ pds,
                const float* __restrict__ Wm,
                float* __restrict__ out,
                const int* __restrict__ flags)
{
    __shared__ double yd[H];
    __shared__ double parts[4 * E];
    __shared__ double ss[256];

    const int t = threadIdx.x;
    const int count = flags[0];

    for (int j = blockIdx.x; j < count; j += gridDim.x) {
        const int r = flags[1 + j];
        const float* xr = x + (size_t)r * H;

        double s = 0.0;
#pragma unroll
        for (int i = 0; i < 8; ++i) {
            const int h = t * 8 + i;
            const double xv = (double)xr[h];
            s += xv * xv;
            yd[h] = xv * (double)pds[h];
        }
        ss[t] = s;
        __syncthreads();

        const int ex = t & 63;
        const int sl = t >> 6;
        const float* wp = Wm + (size_t)(sl * 512) * E + ex;
        double acc = 0.0;
#pragma unroll 8
        for (int h = 0; h < 512; ++h)
            acc = fma(yd[sl * 512 + h], (double)wp[(size_t)h * E], acc);
        parts[sl * E + ex] = acc;
        __syncthreads();

        if (t < 64) {
            const int lane = t;
            double tot = ss[lane * 4] + ss[lane * 4 + 1] + ss[lane * 4 + 2] + ss[lane * 4 + 3];
#pragma unroll
            for (int off = 32; off >= 1; off >>= 1)
                tot += __shfl_xor(tot, off);
            const double sf = (1.0 / sqrt(tot * (1.0 / (double)H) + 1e-6)) * 0.022097086912079608;

            const double Ld = parts[0 * E + lane] + parts[1 * E + lane]
                            + parts[2 * E + lane] + parts[3 * E + lane];
            const float L = (float)(Ld * sf);

            float m = L;
#pragma unroll
            for (int off = 32; off >= 1; off >>= 1)
                m = fmaxf(m, __shfl_xor(m, off));
            const float ev = (float)exp((double)(L - m));
            float S = ev;
#pragma unroll
            for (int off = 32; off >= 1; off >>= 1)
                S += __shfl_xor(S, off);
            const float p = ev / S;

            float v1 = p; int i1 = lane;
#pragma unroll
            for (int off = 32; off >= 1; off >>= 1) {
                const float ov = __shfl_xor(v1, off);
                const int   oi = __shfl_xor(i1, off);
                if (ov > v1 || (ov == v1 && oi < i1)) { v1 = ov; i1 = oi; }
            }
            float v2 = (lane == i1) ? -1.0f : p; int i2 = lane;
#pragma unroll
            for (int off = 32; off >= 1; off >>= 1) {
                const float ov = __shfl_xor(v2, off);
                const int   oi = __shfl_xor(i2, off);
                if (ov > v2 || (ov == v2 && oi < i2)) { v2 = ov; i2 = oi; }
            }

            const float denom = fmaxf(v1 + v2, 1e-9f);
            const float wA = v1 / denom;
            const float wB = v2 / denom;
            const float o  = (lane == i1) ? wA : ((lane == i2) ? wB : 0.0f);
            out[(size_t)r * E + lane] = o;
        }
        __syncthreads();
    }
}

// ============ round-5 fallback (verified) in case ws_size is small ============
__global__ void zero_cnt(int* __restrict__ flags) {
    if (threadIdx.x == 0 && blockIdx.x == 0) flags[0] = 0;
}

__global__ __launch_bounds__(256)
void router_f32(const float* __restrict__ x,
                const float* __restrict__ pds,
                const float* __restrict__ Wm,
                float* __restrict__ out,
                int* __restrict__ flags)
{
    __shared__ __align__(16) float yb[RB * PITCH];
    __shared__ float ssbuf[256];
    __shared__ float sfac[RB];

    const int t    = threadIdx.x;
    const int wv_i = t >> 6;
    const int lane = t & 63;
    const int g    = lane >> 4;
    const int e0   = (lane & 15) << 2;

    const int row0 = blockIdx.x * RB;
    const int srow = t >> 4;
    const int sseg = t & 15;

    const float* xrow = x + (size_t)(row0 + srow) * H;

    float acc[4][4];
#pragma unroll
    for (int a = 0; a < 4; ++a)
#pragma unroll
        for (int b = 0; b < 4; ++b) acc[a][b] = 0.0f;

    float sumsq = 0.0f;
    float4 xv[8];
#pragma unroll
    for (int i = 0; i < 8; ++i)
        xv[i] = *(const float4*)(xrow + sseg * 4 + i * 64);

    for (int c = 0; c < NCH; ++c) {
        const float* pbase = pds + c * CB;
#pragma unroll
        for (int i = 0; i < 8; ++i) {
            const int hl = sseg * 4 + i * 64;
            const float4 a4 = xv[i];
            const float4 p4 = *(const float4*)(pbase + hl);
            sumsq += a4.x * a4.x + a4.y * a4.y + a4.z * a4.z + a4.w * a4.w;
            float4 y4;
            y4.x = a4.x * p4.x; y4.y = a4.y * p4.y;
            y4.z = a4.z * p4.z; y4.w = a4.w * p4.w;
            *(float4*)(&yb[srow * PITCH + hl]) = y4;
        }
        __syncthreads();

        if (c + 1 < NCH) {
            const int h0n = (c + 1) * CB;
#pragma unroll
            for (int i = 0; i < 8; ++i)
                xv[i] = *(const float4*)(xrow + h0n + sseg * 4 + i * 64);
        }

        const int hb = wv_i * 128;
        const float* wbase = Wm + (size_t)(c * CB) * E + e0;
#pragma unroll 2
        for (int s = 0; s < 32; ++s) {
            const int hh = hb + s * 4;
            const float4 w0 = *(const float4*)(wbase + (size_t)(hh + 0) * E);
            const float4 w1 = *(const float4*)(wbase + (size_t)(hh + 1) * E);
            const float4 w2 = *(const float4*)(wbase + (size_t)(hh + 2) * E);
            const float4 w3 = *(const float4*)(wbase + (size_t)(hh + 3) * E);
#pragma unroll
            for (int rr = 0; rr < 4; ++rr) {
                const float4 y4 = *(const float4*)(&yb[(4 * rr + g) * PITCH + hh]);
                acc[rr][0] = fmaf(y4.w, w3.x, fmaf(y4.z, w2.x, fmaf(y4.y, w1.x, fmaf(y4.x, w0.x, acc[rr][0]))));
                acc[rr][1] = fmaf(y4.w, w3.y, fmaf(y4.z, w2.y, fmaf(y4.y, w1.y, fmaf(y4.x, w0.y, acc[rr][1]))));
                acc[rr][2] = fmaf(y4.w, w3.z, fmaf(y4.z, w2.z, fmaf(y4.y, w1.z, fmaf(y4.x, w0.z, acc[rr][2]))));
                acc[rr][3] = fmaf(y4.w, w3.w, fmaf(y4.z, w2.w, fmaf(y4.y, w1.w, fmaf(y4.x, w0.w, acc[rr][3]))));
            }
        }
        __syncthreads();
    }

    ssbuf[t] = sumsq;
    __syncthreads();
    if (t < RB) {
        float tot = 0.0f;
#pragma unroll
        for (int i = 0; i < 16; ++i) tot += ssbuf[t * 16 + i];
        sfac[t] = rsqrtf(tot * (1.0f / (float)H) + 1e-6f) * 0.022097086912079608f;
    }

#pragma unroll
    for (int rr = 0; rr < 4; ++rr) {
        const int r = 4 * rr + g;
        *(float4*)(&yb[((wv_i * RB) + r) * E + e0]) =
            make_float4(acc[rr][0], acc[rr][1], acc[rr][2], acc[rr][3]);
    }
    __syncthreads();

#pragma unroll
    for (int rr = 0; rr < 4; ++rr) {
        const int r = wv_i * 4 + rr;
        float L = yb[(0 * RB + r) * E + lane] + yb[(1 * RB + r) * E + lane]
                + yb[(2 * RB + r) * E + lane] + yb[(3 * RB + r) * E + lane];
        L *= sfac[r];

        float m = L;
#pragma unroll
        for (int off = 32; off >= 1; off >>= 1)
            m = fmaxf(m, __shfl_xor(m, off));
        const float ev = expf(L - m);
        float S = ev;
#pragma unroll
        for (int off = 32; off >= 1; off >>= 1)
            S += __shfl_xor(S, off);
        const float p = ev / S;

        float v1 = p; int i1 = lane;
#pragma unroll
        for (int off = 32; off >= 1; off >>= 1) {
            const float ov = __shfl_xor(v1, off);
            const int   oi = __shfl_xor(i1, off);
            if (ov > v1 || (ov == v1 && oi < i1)) { v1 = ov; i1 = oi; }
        }
        float v2 = (lane == i1) ? -1.0f : p; int i2 = lane;
#pragma unroll
        for (int off = 32; off >= 1; off >>= 1) {
            const float ov = __shfl_xor(v2, off);
            const int   oi = __shfl_xor(i2, off);
            if (ov > v2 || (ov == v2 && oi < i2)) { v2 = ov; i2 = oi; }
        }
        float v3 = (lane == i1 || lane == i2) ? -1.0f : p;
#pragma unroll
        for (int off = 32; off >= 1; off >>= 1)
            v3 = fmaxf(v3, __shfl_xor(v3, off));

        if (lane == 0 && (v2 - v3) < TAU) {
            const int k = atomicAdd(flags, 1);
            flags[1 + k] = row0 + r;
        }

        const float denom = fmaxf(v1 + v2, 1e-9f);
        const float wA = v1 / denom;
        const float wB = v2 / denom;
        const float o  = (lane == i1) ? wA : ((lane == i2) ? wB : 0.0f);
        out[(size_t)(row0 + r) * E + lane] = o;
    }
}

extern "C" void kernel_launch(void* const* d_in, const int* in_sizes, int n_in,
                              void* d_out, int out_size, void* d_ws, size_t ws_size,
                              hipStream_t stream) {
    const float* x   = (const float*)d_in[0];
    const float* pds = (const float*)d_in[1];
    const float* Wm  = (const float*)d_in[2];
    float* out = (float*)d_out;
    int* flags = (int*)d_ws;

    const int T = in_sizes[0] / H;   // 16384

    if (ws_size >= WS_NEEDED) {
        unsigned short* whi = (unsigned short*)((char*)d_ws + WHI_OFF);
        unsigned short* wlo = (unsigned short*)((char*)d_ws + WLO_OFF);
        hipLaunchKernelGGL(prep_w,     dim3(64),     dim3(256), 0, stream, Wm, flags, whi, wlo);
        hipLaunchKernelGGL(router_nb,  dim3(T / MT), dim3(256), 0, stream, x, pds, whi, wlo, out, flags);
        hipLaunchKernelGGL(router_fix, dim3(128),    dim3(256), 0, stream, x, pds, Wm, out, flags);
    } else {
        hipLaunchKernelGGL(zero_cnt,   dim3(1),      dim3(64),  0, stream, flags);
        hipLaunchKernelGGL(router_f32, dim3(T / RB), dim3(256), 0, stream, x, pds, Wm, out, flags);
        hipLaunchKernelGGL(router_fix, dim3(128),    dim3(256), 0, stream, x, pds, Wm, out, flags);
    }
}